// Round 6
// baseline (1007.053 us; speedup 1.0000x reference)
//
#include <hip/hip_runtime.h>
#include <math.h>

#define DD 128
#define SPB 400   // nodes per permute bucket
#define CBM 128   // rows per block in MFMA GEMM kernels

using fragT = __attribute__((ext_vector_type(8))) short;   // 8 bf16
using f32x4 = __attribute__((ext_vector_type(4))) float;

__device__ inline float trunc_bf16(float a) {
    return __uint_as_float(__float_as_uint(a) & 0xFFFF0000u);
}
__device__ inline short bf16bits(float a) {
    return (short)(__float_as_uint(a) >> 16);
}
// Exact 3-way bf16 split: x = f1 + f2 + f3
__device__ inline void split8_3(const float4 v0, const float4 v1,
                                fragT& f1, fragT& f2, fragT& f3) {
    const float x[8] = {v0.x, v0.y, v0.z, v0.w, v1.x, v1.y, v1.z, v1.w};
    #pragma unroll
    for (int j = 0; j < 8; ++j) {
        const float a  = x[j];
        const float t1 = trunc_bf16(a);
        const float r1 = a - t1;
        const float t2 = trunc_bf16(r1);
        const float r2 = r1 - t2;
        f1[j] = bf16bits(a);
        f2[j] = bf16bits(t2);
        f3[j] = bf16bits(r2);
    }
}

// ===========================================================================
// Pack a 128x128 fp32 W ([K][N] row-major) into MFMA-frag order, 3-way split.
// Per 64-K chunk c: [comp(3)][s(2)][t(8)][lane(64)][j(8)] shorts (24576/chunk)
//   k = c*64 + s*32 + (lane>>4)*8 + j ;  n = t*16 + (lane&15)
// (R4-proven, byte-identical; 7 launches.)
// ===========================================================================
__global__ __launch_bounds__(64) void k_pack_cls(
    const float* __restrict__ W, short* __restrict__ packC)
{
    const int b = blockIdx.x;              // 32 blocks
    const int c = b >> 4, s = (b >> 3) & 1, t = b & 7;
    const int l = threadIdx.x;
    const int kg = c * 64 + s * 32 + ((l >> 4) << 3);
    const int n  = t * 16 + (l & 15);
    fragT c1, c2, c3;
    #pragma unroll
    for (int j = 0; j < 8; ++j) {
        const float a  = W[(kg + j) * DD + n];
        const float t1 = trunc_bf16(a);
        const float r1 = a - t1;
        const float t2 = trunc_bf16(r1);
        const float r2 = r1 - t2;
        c1[j] = bf16bits(a);
        c2[j] = bf16bits(t2);
        c3[j] = bf16bits(r2);
    }
    short* base = packC + (size_t)c * 24576 + s * 4096 + t * 512 + l * 8;
    *(fragT*)(base)         = c1;
    *(fragT*)(base + 8192)  = c2;
    *(fragT*)(base + 16384) = c3;
}

// ===========================================================================
// Stage 1 (once per call): counting-sort edges by dst -> CSR
// ===========================================================================
__global__ __launch_bounds__(256) void k_hist(
    const int* __restrict__ dst, int* __restrict__ counts, int E)
{
    int e = blockIdx.x * 256 + threadIdx.x;
    if (e < E) atomicAdd(&counts[dst[e]], 1);
}

__global__ __launch_bounds__(256) void k_scan1(
    const int* cnt, int* excl, int* __restrict__ bsum, int N)
{
    __shared__ int tmp[256];
    const int t = threadIdx.x;
    const int base = blockIdx.x * 1024 + t * 4;
    int v[4];
    #pragma unroll
    for (int i = 0; i < 4; ++i) v[i] = (base + i < N) ? cnt[base + i] : 0;
    const int s = v[0] + v[1] + v[2] + v[3];
    tmp[t] = s;
    __syncthreads();
    int val = s;
    for (int off = 1; off < 256; off <<= 1) {
        int u = (t >= off) ? tmp[t - off] : 0;
        __syncthreads();
        val += u;
        tmp[t] = val;
        __syncthreads();
    }
    int run = val - s;
    #pragma unroll
    for (int i = 0; i < 4; ++i) {
        if (base + i < N) excl[base + i] = run;
        run += v[i];
    }
    if (t == 255) bsum[blockIdx.x] = val;
}

__global__ __launch_bounds__(256) void k_scan2(int* __restrict__ bsum, int nb)
{
    __shared__ int tmp[256];
    const int t = threadIdx.x;
    const int s = (t < nb) ? bsum[t] : 0;
    tmp[t] = s;
    __syncthreads();
    int val = s;
    for (int off = 1; off < 256; off <<= 1) {
        int u = (t >= off) ? tmp[t - off] : 0;
        __syncthreads();
        val += u;
        tmp[t] = val;
        __syncthreads();
    }
    if (t < nb) bsum[t] = val - s;
}

__global__ __launch_bounds__(256) void k_scan3(
    const int* __restrict__ excl, const int* __restrict__ bsum,
    int* __restrict__ starts, int* __restrict__ cursor1, int N, int E)
{
    int i = blockIdx.x * 256 + threadIdx.x;
    if (i < N) {
        int v = excl[i] + bsum[i >> 10];
        starts[i] = v;
        if (i % SPB == 0) cursor1[i / SPB] = v;
        if (i == N - 1) starts[N] = E;
    }
}

// Permute pass 1: coarse-bucket (dst/SPB) with LDS histogram; grouped writes.
__global__ __launch_bounds__(256) void k_bucket(
    const int* __restrict__ src, const int* __restrict__ dst,
    const float* __restrict__ ew, int* __restrict__ cursor1,
    int4* __restrict__ tmp, int E)
{
    __shared__ int hist[256];
    __shared__ int base[256];
    const int t = threadIdx.x;
    const int e0 = blockIdx.x * 2048;
    hist[t] = 0;
    __syncthreads();
    int myb[8], myr[8];
    #pragma unroll
    for (int u = 0; u < 8; ++u) {
        int e = e0 + u * 256 + t;
        if (e < E) {
            int b = dst[e] / SPB;
            myb[u] = b;
            myr[u] = atomicAdd(&hist[b], 1);
        } else myb[u] = -1;
    }
    __syncthreads();
    if (hist[t] > 0) base[t] = atomicAdd(&cursor1[t], hist[t]);
    __syncthreads();
    #pragma unroll
    for (int u = 0; u < 8; ++u) {
        int e = e0 + u * 256 + t;
        if (e < E)
            tmp[base[myb[u]] + myr[u]] =
                make_int4(src[e], dst[e], __float_as_int(ew[e]), 0);
    }
}

// Permute pass 2: one block per bucket; LDS cursors; L2-local placement.
__global__ __launch_bounds__(256) void k_place(
    const int4* __restrict__ tmp, const int* __restrict__ starts,
    int2* __restrict__ edges_s, int N, int E)
{
    __shared__ int cur[SPB];
    const int b  = blockIdx.x;
    const int n0 = b * SPB;
    const int n1 = min(N, n0 + SPB);
    const int t  = threadIdx.x;
    for (int i = t; i < n1 - n0; i += 256) cur[i] = starts[n0 + i];
    __syncthreads();
    const int r0 = starts[n0];
    const int r1 = (n1 < N) ? starts[n1] : E;
    for (int e = r0 + t; e < r1; e += 256) {
        int4 rec = tmp[e];
        int pos = atomicAdd(&cur[rec.y - n0], 1);
        edges_s[pos] = make_int2(rec.x, rec.z);
    }
}

// ===========================================================================
// Gather segment-sum: one wave/node, halves own alternating edges (float4).
// ===========================================================================
__global__ __launch_bounds__(256) void k_gather(
    const float* __restrict__ h, const int* __restrict__ starts,
    const int2* __restrict__ edges, float* __restrict__ agg, int N)
{
    const int w = (blockIdx.x * 256 + threadIdx.x) >> 6;
    if (w >= N) return;
    const int lane = threadIdx.x & 63;
    const int half = lane >> 5;
    const int c4   = (lane & 31) << 2;
    const int s0 = starts[w];
    const int s1 = starts[w + 1];
    float4 a0 = make_float4(0.f, 0.f, 0.f, 0.f);
    float4 a1 = make_float4(0.f, 0.f, 0.f, 0.f);
    int j = s0;
    for (; j + 8 <= s1; j += 8) {
        const int2 eA = edges[j     + half];
        const int2 eB = edges[j + 2 + half];
        const int2 eC = edges[j + 4 + half];
        const int2 eD = edges[j + 6 + half];
        const float4 vA = *(const float4*)(h + (size_t)eA.x * DD + c4);
        const float4 vB = *(const float4*)(h + (size_t)eB.x * DD + c4);
        const float4 vC = *(const float4*)(h + (size_t)eC.x * DD + c4);
        const float4 vD = *(const float4*)(h + (size_t)eD.x * DD + c4);
        const float wA = __int_as_float(eA.y), wB = __int_as_float(eB.y);
        const float wC = __int_as_float(eC.y), wD = __int_as_float(eD.y);
        a0.x = fmaf(vA.x, wA, a0.x); a0.y = fmaf(vA.y, wA, a0.y);
        a0.z = fmaf(vA.z, wA, a0.z); a0.w = fmaf(vA.w, wA, a0.w);
        a1.x = fmaf(vB.x, wB, a1.x); a1.y = fmaf(vB.y, wB, a1.y);
        a1.z = fmaf(vB.z, wB, a1.z); a1.w = fmaf(vB.w, wB, a1.w);
        a0.x = fmaf(vC.x, wC, a0.x); a0.y = fmaf(vC.y, wC, a0.y);
        a0.z = fmaf(vC.z, wC, a0.z); a0.w = fmaf(vC.w, wC, a0.w);
        a1.x = fmaf(vD.x, wD, a1.x); a1.y = fmaf(vD.y, wD, a1.y);
        a1.z = fmaf(vD.z, wD, a1.z); a1.w = fmaf(vD.w, wD, a1.w);
    }
    for (; j < s1; j += 2) {
        const int idx = j + half;
        const bool ok = idx < s1;
        const int2 e = edges[ok ? idx : s1 - 1];
        const float wt = ok ? __int_as_float(e.y) : 0.f;
        const float4 v = *(const float4*)(h + (size_t)e.x * DD + c4);
        a0.x = fmaf(v.x, wt, a0.x); a0.y = fmaf(v.y, wt, a0.y);
        a0.z = fmaf(v.z, wt, a0.z); a0.w = fmaf(v.w, wt, a0.w);
    }
    float4 tot = make_float4(a0.x + a1.x, a0.y + a1.y, a0.z + a1.z, a0.w + a1.w);
    float4 oth;
    oth.x = __shfl_xor(tot.x, 32);
    oth.y = __shfl_xor(tot.y, 32);
    oth.z = __shfl_xor(tot.z, 32);
    oth.w = __shfl_xor(tot.w, 32);
    if (half == 0) {
        tot.x += oth.x; tot.y += oth.y; tot.z += oth.z; tot.w += oth.w;
        *(float4*)(agg + (size_t)w * DD + c4) = tot;
    }
}

// ===========================================================================
// Single-source MFMA GEMM. ONE delta vs the R4-proven version: B fragments
// are read DIRECTLY from packed global memory (96 KB, L2-resident in every
// XCD) instead of being staged through LDS. No LDS, no barriers.
//   addX == 0:  X = A @ W + bias     (bias broadcast per col)
//   addX == 1:  X = A @ W + X
// A NOT __restrict__ (call 1 passes A == X; per-wave rows only, all reads
// precede stores in wave program order). 6-term exact bf16 template.
// ===========================================================================
__global__ __launch_bounds__(256, 3) void k_gemm(
    const float* A, const short* __restrict__ packW,
    const float* __restrict__ bias, float* X, int addX, int N)
{
    const int t256 = threadIdx.x;
    const int lane = t256 & 63;
    const int w    = t256 >> 6;
    const int q    = lane >> 4;
    const int r16  = lane & 15;
    const int rowbase = blockIdx.x * CBM + w * 32;

    f32x4 acc[2][8];
    #pragma unroll
    for (int mt = 0; mt < 2; ++mt)
        #pragma unroll
        for (int t = 0; t < 8; ++t) acc[mt][t] = (f32x4)(0.f);

    #pragma unroll
    for (int c = 0; c < 2; ++c) {
        const int kb = c * 64;
        #pragma unroll
        for (int s = 0; s < 2; ++s) {
            const int kq = kb + s * 32 + q * 8;
            fragT a1[2], a2[2], a3[2];
            #pragma unroll
            for (int mt = 0; mt < 2; ++mt) {
                const int row = rowbase + mt * 16 + r16;
                float4 v0 = make_float4(0.f, 0.f, 0.f, 0.f);
                float4 v1 = make_float4(0.f, 0.f, 0.f, 0.f);
                if (row < N) {
                    v0 = *(const float4*)(A + (size_t)row * DD + kq);
                    v1 = *(const float4*)(A + (size_t)row * DD + kq + 4);
                }
                split8_3(v0, v1, a1[mt], a2[mt], a3[mt]);
            }
            const short* gbase = packW + (size_t)c * 24576 + s * 4096 + lane * 8;
            #pragma unroll
            for (int t = 0; t < 8; ++t) {
                const fragT b1c = *(const fragT*)(gbase + t * 512);
                const fragT b2c = *(const fragT*)(gbase + 8192 + t * 512);
                const fragT b3c = *(const fragT*)(gbase + 16384 + t * 512);
                #pragma unroll
                for (int mt = 0; mt < 2; ++mt) {
                    acc[mt][t] = __builtin_amdgcn_mfma_f32_16x16x32_bf16(a1[mt], b1c, acc[mt][t], 0, 0, 0);
                    acc[mt][t] = __builtin_amdgcn_mfma_f32_16x16x32_bf16(a2[mt], b1c, acc[mt][t], 0, 0, 0);
                    acc[mt][t] = __builtin_amdgcn_mfma_f32_16x16x32_bf16(a1[mt], b2c, acc[mt][t], 0, 0, 0);
                    acc[mt][t] = __builtin_amdgcn_mfma_f32_16x16x32_bf16(a3[mt], b1c, acc[mt][t], 0, 0, 0);
                    acc[mt][t] = __builtin_amdgcn_mfma_f32_16x16x32_bf16(a2[mt], b2c, acc[mt][t], 0, 0, 0);
                    acc[mt][t] = __builtin_amdgcn_mfma_f32_16x16x32_bf16(a1[mt], b3c, acc[mt][t], 0, 0, 0);
                }
            }
        }
    }

    // epilogue: X[row][col] = acc + (addX ? X[row][col] : bias[col])
    #pragma unroll
    for (int mt = 0; mt < 2; ++mt) {
        #pragma unroll
        for (int r = 0; r < 4; ++r) {
            const int row = rowbase + mt * 16 + q * 4 + r;
            if (row < N) {
                #pragma unroll
                for (int t = 0; t < 8; ++t) {
                    const int col = t * 16 + r16;
                    const float base =
                        addX ? X[(size_t)row * DD + col] : bias[col];
                    X[(size_t)row * DD + col] = acc[mt][t][r] + base;
                }
            }
        }
    }
}

// ===========================================================================
// In-place row LayerNorm + PReLU on X [N x 128], fp32 exact.
// One wave per row, 4 rows per 256-thread block; lane owns 2 cols (float2).
// (R4-proven, byte-identical.)
// ===========================================================================
__global__ __launch_bounds__(256) void k_ln(
    float* X, const float* __restrict__ lng, const float* __restrict__ lnb,
    const float* __restrict__ alpha_p, int N)
{
    const int row = blockIdx.x * 4 + (threadIdx.x >> 6);
    if (row >= N) return;
    const int lane = threadIdx.x & 63;
    float2 v = *(float2*)(X + (size_t)row * DD + lane * 2);
    float s  = v.x + v.y;
    float s2 = fmaf(v.x, v.x, v.y * v.y);
    #pragma unroll
    for (int off = 32; off > 0; off >>= 1) {
        s  += __shfl_xor(s,  off, 64);
        s2 += __shfl_xor(s2, off, 64);
    }
    const float mean = s * (1.f / 128.f);
    float var = s2 * (1.f / 128.f) - mean * mean;
    var = var < 0.f ? 0.f : var;
    const float rstd = rsqrtf(var + 1e-5f);
    const float2 g = *(const float2*)(lng + lane * 2);
    const float2 b = *(const float2*)(lnb + lane * 2);
    const float alpha = alpha_p[0];
    float y0 = (v.x - mean) * rstd * g.x + b.x;
    float y1 = (v.y - mean) * rstd * g.y + b.y;
    y0 = (y0 >= 0.f) ? y0 : alpha * y0;
    y1 = (y1 >= 0.f) ? y1 : alpha * y1;
    *(float2*)(X + (size_t)row * DD + lane * 2) = make_float2(y0, y1);
}

// ===========================================================================
// Classifier (MFMA): logits = LN(relu(h @ W1 + b1)) @ W2 + b2
// (R4-proven, byte-identical: LDS staging retained here.)
// ===========================================================================
__global__ __launch_bounds__(256, 3) void k_cls(
    const float* __restrict__ hin, const short* __restrict__ packC,
    const float* __restrict__ b1, const float* __restrict__ lng,
    const float* __restrict__ lnb, const float* __restrict__ W2,
    const float* __restrict__ b2, float* __restrict__ out, int N)
{
    __shared__ short sB[24576];   // one 64-K chunk, 3 components, 48 KB

    const int t256 = threadIdx.x;
    const int lane = t256 & 63;
    const int w    = t256 >> 6;
    const int q    = lane >> 4;
    const int r16  = lane & 15;
    const int rowbase = blockIdx.x * CBM + w * 32;

    f32x4 acc[2][8];
    #pragma unroll
    for (int mt = 0; mt < 2; ++mt)
        #pragma unroll
        for (int t = 0; t < 8; ++t) acc[mt][t] = (f32x4)(0.f);

    for (int c = 0; c < 2; ++c) {
        if (c) __syncthreads();
        {   // copy 48 KB pre-packed chunk (3072 uint4)
            const uint4* srcp = (const uint4*)(packC + (size_t)c * 24576);
            uint4* dstp = (uint4*)sB;
            #pragma unroll
            for (int i = 0; i < 12; ++i)
                dstp[i * 256 + t256] = srcp[i * 256 + t256];
        }
        __syncthreads();

        const int kb = c * 64;
        #pragma unroll
        for (int s = 0; s < 2; ++s) {
            const int kq = kb + s * 32 + q * 8;
            fragT a1[2], a2[2], a3[2];
            #pragma unroll
            for (int mt = 0; mt < 2; ++mt) {
                const int row = rowbase + mt * 16 + r16;
                float4 v0 = make_float4(0.f, 0.f, 0.f, 0.f);
                float4 v1 = make_float4(0.f, 0.f, 0.f, 0.f);
                if (row < N) {
                    v0 = *(const float4*)(hin + (size_t)row * DD + kq);
                    v1 = *(const float4*)(hin + (size_t)row * DD + kq + 4);
                }
                split8_3(v0, v1, a1[mt], a2[mt], a3[mt]);
            }
            const short* sbase = sB + s * 4096 + lane * 8;
            #pragma unroll
            for (int t = 0; t < 8; ++t) {
                const fragT b1c = *(const fragT*)(sbase + t * 512);
                const fragT b2c = *(const fragT*)(sbase + 8192 + t * 512);
                const fragT b3c = *(const fragT*)(sbase + 16384 + t * 512);
                #pragma unroll
                for (int mt = 0; mt < 2; ++mt) {
                    acc[mt][t] = __builtin_amdgcn_mfma_f32_16x16x32_bf16(a1[mt], b1c, acc[mt][t], 0, 0, 0);
                    acc[mt][t] = __builtin_amdgcn_mfma_f32_16x16x32_bf16(a2[mt], b1c, acc[mt][t], 0, 0, 0);
                    acc[mt][t] = __builtin_amdgcn_mfma_f32_16x16x32_bf16(a1[mt], b2c, acc[mt][t], 0, 0, 0);
                    acc[mt][t] = __builtin_amdgcn_mfma_f32_16x16x32_bf16(a3[mt], b1c, acc[mt][t], 0, 0, 0);
                    acc[mt][t] = __builtin_amdgcn_mfma_f32_16x16x32_bf16(a2[mt], b2c, acc[mt][t], 0, 0, 0);
                    acc[mt][t] = __builtin_amdgcn_mfma_f32_16x16x32_bf16(a1[mt], b3c, acc[mt][t], 0, 0, 0);
                }
            }
        }
    }

    float b1v[8], gvv[8], bvv[8], w2c0[8], w2c1[8];
    #pragma unroll
    for (int t = 0; t < 8; ++t) {
        const int col = t * 16 + r16;
        b1v[t] = b1[col]; gvv[t] = lng[col]; bvv[t] = lnb[col];
        const float2 w2 = *(const float2*)(W2 + col * 2);
        w2c0[t] = w2.x; w2c1[t] = w2.y;
    }
    const float b2v0 = b2[0], b2v1 = b2[1];

    #pragma unroll
    for (int mt = 0; mt < 2; ++mt) {
        #pragma unroll
        for (int r = 0; r < 4; ++r) {
            const int row = rowbase + mt * 16 + q * 4 + r;
            float xv[8];
            float s = 0.f, s2 = 0.f;
            #pragma unroll
            for (int t = 0; t < 8; ++t) {
                float x = acc[mt][t][r] + b1v[t];
                x = x > 0.f ? x : 0.f;      // relu
                xv[t] = x; s += x; s2 = fmaf(x, x, s2);
            }
            #pragma unroll
            for (int off = 8; off > 0; off >>= 1) {
                s  += __shfl_xor(s,  off, 16);
                s2 += __shfl_xor(s2, off, 16);
            }
            const float mean = s * (1.f / 128.f);
            float var = s2 * (1.f / 128.f) - mean * mean;
            var = var < 0.f ? 0.f : var;
            const float rstd = rsqrtf(var + 1e-5f);
            float p0 = 0.f, p1 = 0.f;
            #pragma unroll
            for (int t = 0; t < 8; ++t) {
                const float z = (xv[t] - mean) * rstd * gvv[t] + bvv[t];
                p0 = fmaf(z, w2c0[t], p0);
                p1 = fmaf(z, w2c1[t], p1);
            }
            #pragma unroll
            for (int off = 8; off > 0; off >>= 1) {
                p0 += __shfl_xor(p0, off, 16);
                p1 += __shfl_xor(p1, off, 16);
            }
            if (r16 == 0 && row < N) {
                out[row * 2 + 0] = p0 + b2v0;
                out[row * 2 + 1] = p1 + b2v1;
            }
        }
    }
}

// ===========================================================================
extern "C" void kernel_launch(void* const* d_in, const int* in_sizes, int n_in,
                              void* d_out, int out_size, void* d_ws, size_t ws_size,
                              hipStream_t stream) {
    const float* features = (const float*)d_in[0];
    const int*   eidx     = (const int*)  d_in[1];
    const float* ew       = (const float*)d_in[2];
    const float* Wrel     = (const float*)d_in[3];
    const float* Wroot    = (const float*)d_in[4];
    const float* bias     = (const float*)d_in[5];
    const float* lng      = (const float*)d_in[6];
    const float* lnb      = (const float*)d_in[7];
    const float* alpha    = (const float*)d_in[8];
    const float* W1       = (const float*)d_in[9];
    const float* b1       = (const float*)d_in[10];
    const float* clng     = (const float*)d_in[11];
    const float* clnb     = (const float*)d_in[12];
    const float* W2       = (const float*)d_in[13];
    const float* b2       = (const float*)d_in[14];

    const int N = in_sizes[0] / DD;
    const int E = in_sizes[2];
    const int L = in_sizes[8];

    // workspace (~116.8 MB of >=155 MB)
    float* bufA    = (float*)d_ws;                   // N*128 f
    float* bufB    = bufA + (size_t)N * DD;          // N*128 f
    int2*  edges_s = (int2*)(bufB + (size_t)N * DD); // E
    int*   counts  = (int*)(edges_s + E);            // N (scanned in-place)
    int*   starts  = counts + N;                     // N+1 (pristine + sentinel)
    int*   bsum    = starts + N + 1;                 // 258
    int*   cursor1 = bsum + 258;                     // 256 (+2 pad -> 16B align)
    short* packAll = (short*)(cursor1 + 258);        // (2L+1)*49152 shorts
    int4*  tmp     = (int4*)bufA;                    // E recs, dead before layers

    const int* src = eidx;
    const int* dst = eidx + E;

    const int eb      = (E + 255) / 256;
    const int eb2k    = (E + 2047) / 2048;
    const int nb      = (N + 1023) / 1024;
    const int NBk     = (N + SPB - 1) / SPB;
    const int mm_blocks  = (N + CBM - 1) / CBM;
    const int ln_blocks  = (N + 3) / 4;
    const int ga_blocks  = (N * 64 + 255) / 256;

    // ---- pack all weight matrices (W_rel[l], W_root[l], cls W1) ----
    for (int l = 0; l < L; ++l) {
        k_pack_cls<<<32, 64, 0, stream>>>(Wrel  + (size_t)l * DD * DD,
                                          packAll + (size_t)(2 * l)     * 49152);
        k_pack_cls<<<32, 64, 0, stream>>>(Wroot + (size_t)l * DD * DD,
                                          packAll + (size_t)(2 * l + 1) * 49152);
    }
    k_pack_cls<<<32, 64, 0, stream>>>(W1, packAll + (size_t)(2 * L) * 49152);

    // ---- build CSR by dst (once per call) ----
    hipMemsetAsync(counts, 0, (size_t)N * sizeof(int), stream);
    k_hist  <<<eb, 256, 0, stream>>>(dst, counts, E);
    k_scan1 <<<nb, 256, 0, stream>>>(counts, counts, bsum, N);   // in-place
    k_scan2 <<<1,  256, 0, stream>>>(bsum, nb);
    k_scan3 <<<(N + 255) / 256, 256, 0, stream>>>(counts, bsum, starts, cursor1, N, E);
    k_bucket<<<eb2k, 256, 0, stream>>>(src, dst, ew, cursor1, tmp, E);
    k_place <<<NBk, 256, 0, stream>>>(tmp, starts, edges_s, N, E);

    // ---- layers: gather -> GEMM(Wrel,+bias) -> GEMM(Wroot,+X) -> LN ----
    const float* hin = features;
    for (int l = 0; l < L; ++l) {
        float* agg = (l & 1) ? bufB : bufA;   // X aliases agg (per-wave safe)
        k_gather<<<ga_blocks, 256, 0, stream>>>(hin, starts, edges_s, agg, N);
        k_gemm<<<mm_blocks, 256, 0, stream>>>(
            agg, packAll + (size_t)(2 * l) * 49152,
            bias + l * DD, agg, 0, N);
        k_gemm<<<mm_blocks, 256, 0, stream>>>(
            hin, packAll + (size_t)(2 * l + 1) * 49152,
            bias + l * DD, agg, 1, N);
        k_ln<<<ln_blocks, 256, 0, stream>>>(
            agg, lng + l * DD, lnb + l * DD, alpha + l, N);
        hin = agg;
    }
    k_cls<<<mm_blocks, 256, 0, stream>>>(hin, packAll + (size_t)(2 * L) * 49152,
                                         b1, clng, clnb, W2, b2,
                                         (float*)d_out, N);
}

// Round 7
// 877.944 us; speedup vs baseline: 1.1471x; 1.1471x over previous
//
#include <hip/hip_runtime.h>
#include <math.h>

#define DD 128
#define SPB 400   // nodes per permute bucket
#define CBM 128   // rows per block in MFMA GEMM kernels

using fragT = __attribute__((ext_vector_type(8))) short;   // 8 bf16
using f32x4 = __attribute__((ext_vector_type(4))) float;

__device__ inline float trunc_bf16(float a) {
    return __uint_as_float(__float_as_uint(a) & 0xFFFF0000u);
}
__device__ inline short bf16bits(float a) {
    return (short)(__float_as_uint(a) >> 16);
}
__device__ inline unsigned short bf16rne(float f) {   // round-to-nearest-even
    unsigned int u = __float_as_uint(f);
    return (unsigned short)((u + 0x7FFFu + ((u >> 16) & 1u)) >> 16);
}
__device__ inline float b2f(unsigned short u) {
    return __uint_as_float((unsigned int)u << 16);
}
// Exact 3-way bf16 split: x = f1 + f2 + f3
__device__ inline void split8_3(const float4 v0, const float4 v1,
                                fragT& f1, fragT& f2, fragT& f3) {
    const float x[8] = {v0.x, v0.y, v0.z, v0.w, v1.x, v1.y, v1.z, v1.w};
    #pragma unroll
    for (int j = 0; j < 8; ++j) {
        const float a  = x[j];
        const float t1 = trunc_bf16(a);
        const float r1 = a - t1;
        const float t2 = trunc_bf16(r1);
        const float r2 = r1 - t2;
        f1[j] = bf16bits(a);
        f2[j] = bf16bits(t2);
        f3[j] = bf16bits(r2);
    }
}

// ===========================================================================
// Pack a 128x128 fp32 W ([K][N] row-major) into MFMA-frag order, 3-way split.
// Per 64-K chunk c: [comp(3)][s(2)][t(8)][lane(64)][j(8)] shorts (24576/chunk)
//   k = c*64 + s*32 + (lane>>4)*8 + j ;  n = t*16 + (lane&15)
// (R4-proven, byte-identical; 7 launches.)
// ===========================================================================
__global__ __launch_bounds__(64) void k_pack_cls(
    const float* __restrict__ W, short* __restrict__ packC)
{
    const int b = blockIdx.x;              // 32 blocks
    const int c = b >> 4, s = (b >> 3) & 1, t = b & 7;
    const int l = threadIdx.x;
    const int kg = c * 64 + s * 32 + ((l >> 4) << 3);
    const int n  = t * 16 + (l & 15);
    fragT c1, c2, c3;
    #pragma unroll
    for (int j = 0; j < 8; ++j) {
        const float a  = W[(kg + j) * DD + n];
        const float t1 = trunc_bf16(a);
        const float r1 = a - t1;
        const float t2 = trunc_bf16(r1);
        const float r2 = r1 - t2;
        c1[j] = bf16bits(a);
        c2[j] = bf16bits(t2);
        c3[j] = bf16bits(r2);
    }
    short* base = packC + (size_t)c * 24576 + s * 4096 + t * 512 + l * 8;
    *(fragT*)(base)         = c1;
    *(fragT*)(base + 8192)  = c2;
    *(fragT*)(base + 16384) = c3;
}

// ===========================================================================
// One-time fp32 -> bf16 (RNE) conversion of features.
// ===========================================================================
__global__ __launch_bounds__(256) void k_tobf16(
    const float* __restrict__ in, unsigned short* __restrict__ out, int n4)
{
    int i = blockIdx.x * 256 + threadIdx.x;
    if (i < n4) {
        const float4 v = ((const float4*)in)[i];
        ushort4 o;
        o.x = bf16rne(v.x); o.y = bf16rne(v.y);
        o.z = bf16rne(v.z); o.w = bf16rne(v.w);
        ((ushort4*)out)[i] = o;
    }
}

// ===========================================================================
// Stage 1 (once per call): counting-sort edges by dst -> CSR
// ===========================================================================
__global__ __launch_bounds__(256) void k_hist(
    const int* __restrict__ dst, int* __restrict__ counts, int E)
{
    int e = blockIdx.x * 256 + threadIdx.x;
    if (e < E) atomicAdd(&counts[dst[e]], 1);
}

__global__ __launch_bounds__(256) void k_scan1(
    const int* cnt, int* excl, int* __restrict__ bsum, int N)
{
    __shared__ int tmp[256];
    const int t = threadIdx.x;
    const int base = blockIdx.x * 1024 + t * 4;
    int v[4];
    #pragma unroll
    for (int i = 0; i < 4; ++i) v[i] = (base + i < N) ? cnt[base + i] : 0;
    const int s = v[0] + v[1] + v[2] + v[3];
    tmp[t] = s;
    __syncthreads();
    int val = s;
    for (int off = 1; off < 256; off <<= 1) {
        int u = (t >= off) ? tmp[t - off] : 0;
        __syncthreads();
        val += u;
        tmp[t] = val;
        __syncthreads();
    }
    int run = val - s;
    #pragma unroll
    for (int i = 0; i < 4; ++i) {
        if (base + i < N) excl[base + i] = run;
        run += v[i];
    }
    if (t == 255) bsum[blockIdx.x] = val;
}

__global__ __launch_bounds__(256) void k_scan2(int* __restrict__ bsum, int nb)
{
    __shared__ int tmp[256];
    const int t = threadIdx.x;
    const int s = (t < nb) ? bsum[t] : 0;
    tmp[t] = s;
    __syncthreads();
    int val = s;
    for (int off = 1; off < 256; off <<= 1) {
        int u = (t >= off) ? tmp[t - off] : 0;
        __syncthreads();
        val += u;
        tmp[t] = val;
        __syncthreads();
    }
    if (t < nb) bsum[t] = val - s;
}

__global__ __launch_bounds__(256) void k_scan3(
    const int* __restrict__ excl, const int* __restrict__ bsum,
    int* __restrict__ starts, int* __restrict__ cursor1, int N, int E)
{
    int i = blockIdx.x * 256 + threadIdx.x;
    if (i < N) {
        int v = excl[i] + bsum[i >> 10];
        starts[i] = v;
        if (i % SPB == 0) cursor1[i / SPB] = v;
        if (i == N - 1) starts[N] = E;
    }
}

// Permute pass 1: coarse-bucket (dst/SPB) with LDS histogram; grouped writes.
__global__ __launch_bounds__(256) void k_bucket(
    const int* __restrict__ src, const int* __restrict__ dst,
    const float* __restrict__ ew, int* __restrict__ cursor1,
    int4* __restrict__ tmp, int E)
{
    __shared__ int hist[256];
    __shared__ int base[256];
    const int t = threadIdx.x;
    const int e0 = blockIdx.x * 2048;
    hist[t] = 0;
    __syncthreads();
    int myb[8], myr[8];
    #pragma unroll
    for (int u = 0; u < 8; ++u) {
        int e = e0 + u * 256 + t;
        if (e < E) {
            int b = dst[e] / SPB;
            myb[u] = b;
            myr[u] = atomicAdd(&hist[b], 1);
        } else myb[u] = -1;
    }
    __syncthreads();
    if (hist[t] > 0) base[t] = atomicAdd(&cursor1[t], hist[t]);
    __syncthreads();
    #pragma unroll
    for (int u = 0; u < 8; ++u) {
        int e = e0 + u * 256 + t;
        if (e < E)
            tmp[base[myb[u]] + myr[u]] =
                make_int4(src[e], dst[e], __float_as_int(ew[e]), 0);
    }
}

// Permute pass 2: one block per bucket; LDS cursors; L2-local placement.
__global__ __launch_bounds__(256) void k_place(
    const int4* __restrict__ tmp, const int* __restrict__ starts,
    int2* __restrict__ edges_s, int N, int E)
{
    __shared__ int cur[SPB];
    const int b  = blockIdx.x;
    const int n0 = b * SPB;
    const int n1 = min(N, n0 + SPB);
    const int t  = threadIdx.x;
    for (int i = t; i < n1 - n0; i += 256) cur[i] = starts[n0 + i];
    __syncthreads();
    const int r0 = starts[n0];
    const int r1 = (n1 < N) ? starts[n1] : E;
    for (int e = r0 + t; e < r1; e += 256) {
        int4 rec = tmp[e];
        int pos = atomicAdd(&cur[rec.y - n0], 1);
        edges_s[pos] = make_int2(rec.x, rec.z);
    }
}

// ===========================================================================
// Gather segment-sum from BF16 h (256 B/row -> halves the 8x-XCD-replicated
// fetch traffic). One wave/node; halves own alternating edges; lane owns
// 4 bf16 columns (8 B load). Accumulation and agg output remain fp32.
// ===========================================================================
__global__ __launch_bounds__(256) void k_gather_bf16(
    const unsigned short* __restrict__ hb, const int* __restrict__ starts,
    const int2* __restrict__ edges, float* __restrict__ agg, int N)
{
    const int w = (blockIdx.x * 256 + threadIdx.x) >> 6;
    if (w >= N) return;
    const int lane = threadIdx.x & 63;
    const int half = lane >> 5;
    const int c4   = (lane & 31) << 2;
    const int s0 = starts[w];
    const int s1 = starts[w + 1];
    float4 a0 = make_float4(0.f, 0.f, 0.f, 0.f);
    float4 a1 = make_float4(0.f, 0.f, 0.f, 0.f);
    int j = s0;
    for (; j + 8 <= s1; j += 8) {
        const int2 eA = edges[j     + half];
        const int2 eB = edges[j + 2 + half];
        const int2 eC = edges[j + 4 + half];
        const int2 eD = edges[j + 6 + half];
        const ushort4 vA = *(const ushort4*)(hb + (size_t)eA.x * DD + c4);
        const ushort4 vB = *(const ushort4*)(hb + (size_t)eB.x * DD + c4);
        const ushort4 vC = *(const ushort4*)(hb + (size_t)eC.x * DD + c4);
        const ushort4 vD = *(const ushort4*)(hb + (size_t)eD.x * DD + c4);
        const float wA = __int_as_float(eA.y), wB = __int_as_float(eB.y);
        const float wC = __int_as_float(eC.y), wD = __int_as_float(eD.y);
        a0.x = fmaf(b2f(vA.x), wA, a0.x); a0.y = fmaf(b2f(vA.y), wA, a0.y);
        a0.z = fmaf(b2f(vA.z), wA, a0.z); a0.w = fmaf(b2f(vA.w), wA, a0.w);
        a1.x = fmaf(b2f(vB.x), wB, a1.x); a1.y = fmaf(b2f(vB.y), wB, a1.y);
        a1.z = fmaf(b2f(vB.z), wB, a1.z); a1.w = fmaf(b2f(vB.w), wB, a1.w);
        a0.x = fmaf(b2f(vC.x), wC, a0.x); a0.y = fmaf(b2f(vC.y), wC, a0.y);
        a0.z = fmaf(b2f(vC.z), wC, a0.z); a0.w = fmaf(b2f(vC.w), wC, a0.w);
        a1.x = fmaf(b2f(vD.x), wD, a1.x); a1.y = fmaf(b2f(vD.y), wD, a1.y);
        a1.z = fmaf(b2f(vD.z), wD, a1.z); a1.w = fmaf(b2f(vD.w), wD, a1.w);
    }
    for (; j < s1; j += 2) {
        const int idx = j + half;
        const bool ok = idx < s1;
        const int2 e = edges[ok ? idx : s1 - 1];
        const float wt = ok ? __int_as_float(e.y) : 0.f;
        const ushort4 v = *(const ushort4*)(hb + (size_t)e.x * DD + c4);
        a0.x = fmaf(b2f(v.x), wt, a0.x); a0.y = fmaf(b2f(v.y), wt, a0.y);
        a0.z = fmaf(b2f(v.z), wt, a0.z); a0.w = fmaf(b2f(v.w), wt, a0.w);
    }
    float4 tot = make_float4(a0.x + a1.x, a0.y + a1.y, a0.z + a1.z, a0.w + a1.w);
    float4 oth;
    oth.x = __shfl_xor(tot.x, 32);
    oth.y = __shfl_xor(tot.y, 32);
    oth.z = __shfl_xor(tot.z, 32);
    oth.w = __shfl_xor(tot.w, 32);
    if (half == 0) {
        tot.x += oth.x; tot.y += oth.y; tot.z += oth.z; tot.w += oth.w;
        *(float4*)(agg + (size_t)w * DD + c4) = tot;
    }
}

// ===========================================================================
// Single-source MFMA GEMM (R4-proven, byte-identical: LDS-staged B):
//   addX == 0:  X = A @ W + bias     (bias broadcast per col)
//   addX == 1:  X = A @ W + X
// A is NOT __restrict__ (call 1 passes A == X; all A reads precede stores,
// block-local rows only). packW = 2 chunks of 24576 shorts (3 comps).
// ===========================================================================
__global__ __launch_bounds__(256, 3) void k_gemm(
    const float* A, const short* __restrict__ packW,
    const float* __restrict__ bias, float* X, int addX, int N)
{
    __shared__ short sB[24576];   // one 64-K chunk, 3 components, 48 KB

    const int t256 = threadIdx.x;
    const int lane = t256 & 63;
    const int w    = t256 >> 6;
    const int q    = lane >> 4;
    const int r16  = lane & 15;
    const int rowbase = blockIdx.x * CBM + w * 32;

    f32x4 acc[2][8];
    #pragma unroll
    for (int mt = 0; mt < 2; ++mt)
        #pragma unroll
        for (int t = 0; t < 8; ++t) acc[mt][t] = (f32x4)(0.f);

    for (int c = 0; c < 2; ++c) {
        if (c) __syncthreads();
        {   // copy 48 KB pre-packed chunk (3072 uint4)
            const uint4* srcp = (const uint4*)(packW + (size_t)c * 24576);
            uint4* dstp = (uint4*)sB;
            #pragma unroll
            for (int i = 0; i < 12; ++i)
                dstp[i * 256 + t256] = srcp[i * 256 + t256];
        }
        __syncthreads();

        const int kb = c * 64;
        #pragma unroll
        for (int s = 0; s < 2; ++s) {
            const int kq = kb + s * 32 + q * 8;
            fragT a1[2], a2[2], a3[2];
            #pragma unroll
            for (int mt = 0; mt < 2; ++mt) {
                const int row = rowbase + mt * 16 + r16;
                float4 v0 = make_float4(0.f, 0.f, 0.f, 0.f);
                float4 v1 = make_float4(0.f, 0.f, 0.f, 0.f);
                if (row < N) {
                    v0 = *(const float4*)(A + (size_t)row * DD + kq);
                    v1 = *(const float4*)(A + (size_t)row * DD + kq + 4);
                }
                split8_3(v0, v1, a1[mt], a2[mt], a3[mt]);
            }
            const short* sbase = sB + s * 4096 + lane * 8;
            #pragma unroll
            for (int t = 0; t < 8; ++t) {
                const fragT b1c = *(const fragT*)(sbase + t * 512);
                const fragT b2c = *(const fragT*)(sbase + 8192 + t * 512);
                const fragT b3c = *(const fragT*)(sbase + 16384 + t * 512);
                #pragma unroll
                for (int mt = 0; mt < 2; ++mt) {
                    acc[mt][t] = __builtin_amdgcn_mfma_f32_16x16x32_bf16(a1[mt], b1c, acc[mt][t], 0, 0, 0);
                    acc[mt][t] = __builtin_amdgcn_mfma_f32_16x16x32_bf16(a2[mt], b1c, acc[mt][t], 0, 0, 0);
                    acc[mt][t] = __builtin_amdgcn_mfma_f32_16x16x32_bf16(a1[mt], b2c, acc[mt][t], 0, 0, 0);
                    acc[mt][t] = __builtin_amdgcn_mfma_f32_16x16x32_bf16(a3[mt], b1c, acc[mt][t], 0, 0, 0);
                    acc[mt][t] = __builtin_amdgcn_mfma_f32_16x16x32_bf16(a2[mt], b2c, acc[mt][t], 0, 0, 0);
                    acc[mt][t] = __builtin_amdgcn_mfma_f32_16x16x32_bf16(a1[mt], b3c, acc[mt][t], 0, 0, 0);
                }
            }
        }
    }

    // epilogue: X[row][col] = acc + (addX ? X[row][col] : bias[col])
    #pragma unroll
    for (int mt = 0; mt < 2; ++mt) {
        #pragma unroll
        for (int r = 0; r < 4; ++r) {
            const int row = rowbase + mt * 16 + q * 4 + r;
            if (row < N) {
                #pragma unroll
                for (int t = 0; t < 8; ++t) {
                    const int col = t * 16 + r16;
                    const float base =
                        addX ? X[(size_t)row * DD + col] : bias[col];
                    X[(size_t)row * DD + col] = acc[mt][t][r] + base;
                }
            }
        }
    }
}

// ===========================================================================
// In-place row LayerNorm + PReLU on X [N x 128], fp32 exact; additionally
// emits a bf16(RNE) copy into hb (for the next layer's gather) when hb!=0.
// One wave per row, 4 rows per 256-thread block; lane owns 2 cols (float2).
// ===========================================================================
__global__ __launch_bounds__(256) void k_ln(
    float* X, unsigned short* hb,
    const float* __restrict__ lng, const float* __restrict__ lnb,
    const float* __restrict__ alpha_p, int N)
{
    const int row = blockIdx.x * 4 + (threadIdx.x >> 6);
    if (row >= N) return;
    const int lane = threadIdx.x & 63;
    float2 v = *(float2*)(X + (size_t)row * DD + lane * 2);
    float s  = v.x + v.y;
    float s2 = fmaf(v.x, v.x, v.y * v.y);
    #pragma unroll
    for (int off = 32; off > 0; off >>= 1) {
        s  += __shfl_xor(s,  off, 64);
        s2 += __shfl_xor(s2, off, 64);
    }
    const float mean = s * (1.f / 128.f);
    float var = s2 * (1.f / 128.f) - mean * mean;
    var = var < 0.f ? 0.f : var;
    const float rstd = rsqrtf(var + 1e-5f);
    const float2 g = *(const float2*)(lng + lane * 2);
    const float2 b = *(const float2*)(lnb + lane * 2);
    const float alpha = alpha_p[0];
    float y0 = (v.x - mean) * rstd * g.x + b.x;
    float y1 = (v.y - mean) * rstd * g.y + b.y;
    y0 = (y0 >= 0.f) ? y0 : alpha * y0;
    y1 = (y1 >= 0.f) ? y1 : alpha * y1;
    *(float2*)(X + (size_t)row * DD + lane * 2) = make_float2(y0, y1);
    if (hb) {
        ushort2 hv;
        hv.x = bf16rne(y0);
        hv.y = bf16rne(y1);
        *(ushort2*)(hb + (size_t)row * DD + lane * 2) = hv;
    }
}

// ===========================================================================
// Classifier (MFMA): logits = LN(relu(h @ W1 + b1)) @ W2 + b2
// (R4-proven, byte-identical.)
// ===========================================================================
__global__ __launch_bounds__(256, 3) void k_cls(
    const float* __restrict__ hin, const short* __restrict__ packC,
    const float* __restrict__ b1, const float* __restrict__ lng,
    const float* __restrict__ lnb, const float* __restrict__ W2,
    const float* __restrict__ b2, float* __restrict__ out, int N)
{
    __shared__ short sB[24576];   // one 64-K chunk, 3 components, 48 KB

    const int t256 = threadIdx.x;
    const int lane = t256 & 63;
    const int w    = t256 >> 6;
    const int q    = lane >> 4;
    const int r16  = lane & 15;
    const int rowbase = blockIdx.x * CBM + w * 32;

    f32x4 acc[2][8];
    #pragma unroll
    for (int mt = 0; mt < 2; ++mt)
        #pragma unroll
        for (int t = 0; t < 8; ++t) acc[mt][t] = (f32x4)(0.f);

    for (int c = 0; c < 2; ++c) {
        if (c) __syncthreads();
        {   // copy 48 KB pre-packed chunk (3072 uint4)
            const uint4* srcp = (const uint4*)(packC + (size_t)c * 24576);
            uint4* dstp = (uint4*)sB;
            #pragma unroll
            for (int i = 0; i < 12; ++i)
                dstp[i * 256 + t256] = srcp[i * 256 + t256];
        }
        __syncthreads();

        const int kb = c * 64;
        #pragma unroll
        for (int s = 0; s < 2; ++s) {
            const int kq = kb + s * 32 + q * 8;
            fragT a1[2], a2[2], a3[2];
            #pragma unroll
            for (int mt = 0; mt < 2; ++mt) {
                const int row = rowbase + mt * 16 + r16;
                float4 v0 = make_float4(0.f, 0.f, 0.f, 0.f);
                float4 v1 = make_float4(0.f, 0.f, 0.f, 0.f);
                if (row < N) {
                    v0 = *(const float4*)(hin + (size_t)row * DD + kq);
                    v1 = *(const float4*)(hin + (size_t)row * DD + kq + 4);
                }
                split8_3(v0, v1, a1[mt], a2[mt], a3[mt]);
            }
            const short* sbase = sB + s * 4096 + lane * 8;
            #pragma unroll
            for (int t = 0; t < 8; ++t) {
                const fragT b1c = *(const fragT*)(sbase + t * 512);
                const fragT b2c = *(const fragT*)(sbase + 8192 + t * 512);
                const fragT b3c = *(const fragT*)(sbase + 16384 + t * 512);
                #pragma unroll
                for (int mt = 0; mt < 2; ++mt) {
                    acc[mt][t] = __builtin_amdgcn_mfma_f32_16x16x32_bf16(a1[mt], b1c, acc[mt][t], 0, 0, 0);
                    acc[mt][t] = __builtin_amdgcn_mfma_f32_16x16x32_bf16(a2[mt], b1c, acc[mt][t], 0, 0, 0);
                    acc[mt][t] = __builtin_amdgcn_mfma_f32_16x16x32_bf16(a1[mt], b2c, acc[mt][t], 0, 0, 0);
                    acc[mt][t] = __builtin_amdgcn_mfma_f32_16x16x32_bf16(a3[mt], b1c, acc[mt][t], 0, 0, 0);
                    acc[mt][t] = __builtin_amdgcn_mfma_f32_16x16x32_bf16(a2[mt], b2c, acc[mt][t], 0, 0, 0);
                    acc[mt][t] = __builtin_amdgcn_mfma_f32_16x16x32_bf16(a1[mt], b3c, acc[mt][t], 0, 0, 0);
                }
            }
        }
    }

    float b1v[8], gvv[8], bvv[8], w2c0[8], w2c1[8];
    #pragma unroll
    for (int t = 0; t < 8; ++t) {
        const int col = t * 16 + r16;
        b1v[t] = b1[col]; gvv[t] = lng[col]; bvv[t] = lnb[col];
        const float2 w2 = *(const float2*)(W2 + col * 2);
        w2c0[t] = w2.x; w2c1[t] = w2.y;
    }
    const float b2v0 = b2[0], b2v1 = b2[1];

    #pragma unroll
    for (int mt = 0; mt < 2; ++mt) {
        #pragma unroll
        for (int r = 0; r < 4; ++r) {
            const int row = rowbase + mt * 16 + q * 4 + r;
            float xv[8];
            float s = 0.f, s2 = 0.f;
            #pragma unroll
            for (int t = 0; t < 8; ++t) {
                float x = acc[mt][t][r] + b1v[t];
                x = x > 0.f ? x : 0.f;      // relu
                xv[t] = x; s += x; s2 = fmaf(x, x, s2);
            }
            #pragma unroll
            for (int off = 8; off > 0; off >>= 1) {
                s  += __shfl_xor(s,  off, 16);
                s2 += __shfl_xor(s2, off, 16);
            }
            const float mean = s * (1.f / 128.f);
            float var = s2 * (1.f / 128.f) - mean * mean;
            var = var < 0.f ? 0.f : var;
            const float rstd = rsqrtf(var + 1e-5f);
            float p0 = 0.f, p1 = 0.f;
            #pragma unroll
            for (int t = 0; t < 8; ++t) {
                const float z = (xv[t] - mean) * rstd * gvv[t] + bvv[t];
                p0 = fmaf(z, w2c0[t], p0);
                p1 = fmaf(z, w2c1[t], p1);
            }
            #pragma unroll
            for (int off = 8; off > 0; off >>= 1) {
                p0 += __shfl_xor(p0, off, 16);
                p1 += __shfl_xor(p1, off, 16);
            }
            if (r16 == 0 && row < N) {
                out[row * 2 + 0] = p0 + b2v0;
                out[row * 2 + 1] = p1 + b2v1;
            }
        }
    }
}

// ===========================================================================
extern "C" void kernel_launch(void* const* d_in, const int* in_sizes, int n_in,
                              void* d_out, int out_size, void* d_ws, size_t ws_size,
                              hipStream_t stream) {
    const float* features = (const float*)d_in[0];
    const int*   eidx     = (const int*)  d_in[1];
    const float* ew       = (const float*)d_in[2];
    const float* Wrel     = (const float*)d_in[3];
    const float* Wroot    = (const float*)d_in[4];
    const float* bias     = (const float*)d_in[5];
    const float* lng      = (const float*)d_in[6];
    const float* lnb      = (const float*)d_in[7];
    const float* alpha    = (const float*)d_in[8];
    const float* W1       = (const float*)d_in[9];
    const float* b1       = (const float*)d_in[10];
    const float* clng     = (const float*)d_in[11];
    const float* clnb     = (const float*)d_in[12];
    const float* W2       = (const float*)d_in[13];
    const float* b2       = (const float*)d_in[14];

    const int N = in_sizes[0] / DD;
    const int E = in_sizes[2];
    const int L = in_sizes[8];

    // workspace (~142.3 MB of >=155 MB)
    float* bufA    = (float*)d_ws;                   // N*128 f
    float* bufB    = bufA + (size_t)N * DD;          // N*128 f
    int2*  edges_s = (int2*)(bufB + (size_t)N * DD); // E
    int*   counts  = (int*)(edges_s + E);            // N (scanned in-place)
    int*   starts  = counts + N;                     // N+1 (pristine + sentinel)
    int*   bsum    = starts + N + 1;                 // 258
    int*   cursor1 = bsum + 258;                     // 256 (+2 pad)
    unsigned short* hb = (unsigned short*)(cursor1 + 261);  // N*128 bf16, 16B-aligned
    short* packAll = (short*)(hb + (size_t)N * DD);  // (2L+1)*49152 shorts
    int4*  tmp     = (int4*)bufA;                    // E recs, dead before layers

    const int* src = eidx;
    const int* dst = eidx + E;

    const int eb      = (E + 255) / 256;
    const int eb2k    = (E + 2047) / 2048;
    const int nb      = (N + 1023) / 1024;
    const int NBk     = (N + SPB - 1) / SPB;
    const int mm_blocks  = (N + CBM - 1) / CBM;
    const int ln_blocks  = (N + 3) / 4;
    const int ga_blocks  = (N * 64 + 255) / 256;
    const int cv_blocks  = (N * DD / 4 + 255) / 256;

    // ---- pack all weight matrices (W_rel[l], W_root[l], cls W1) ----
    for (int l = 0; l < L; ++l) {
        k_pack_cls<<<32, 64, 0, stream>>>(Wrel  + (size_t)l * DD * DD,
                                          packAll + (size_t)(2 * l)     * 49152);
        k_pack_cls<<<32, 64, 0, stream>>>(Wroot + (size_t)l * DD * DD,
                                          packAll + (size_t)(2 * l + 1) * 49152);
    }
    k_pack_cls<<<32, 64, 0, stream>>>(W1, packAll + (size_t)(2 * L) * 49152);

    // ---- features -> bf16 (for layer-0 gather) ----
    k_tobf16<<<cv_blocks, 256, 0, stream>>>(features, hb, N * DD / 4);

    // ---- build CSR by dst (once per call) ----
    hipMemsetAsync(counts, 0, (size_t)N * sizeof(int), stream);
    k_hist  <<<eb, 256, 0, stream>>>(dst, counts, E);
    k_scan1 <<<nb, 256, 0, stream>>>(counts, counts, bsum, N);   // in-place
    k_scan2 <<<1,  256, 0, stream>>>(bsum, nb);
    k_scan3 <<<(N + 255) / 256, 256, 0, stream>>>(counts, bsum, starts, cursor1, N, E);
    k_bucket<<<eb2k, 256, 0, stream>>>(src, dst, ew, cursor1, tmp, E);
    k_place <<<NBk, 256, 0, stream>>>(tmp, starts, edges_s, N, E);

    // ---- layers: gather(bf16) -> GEMM(Wrel,+bias) -> GEMM(Wroot,+X) -> LN ----
    const float* hin = features;
    for (int l = 0; l < L; ++l) {
        float* agg = (l & 1) ? bufB : bufA;   // X aliases agg (block-local safe)
        k_gather_bf16<<<ga_blocks, 256, 0, stream>>>(hb, starts, edges_s, agg, N);
        k_gemm<<<mm_blocks, 256, 0, stream>>>(
            agg, packAll + (size_t)(2 * l) * 49152,
            bias + l * DD, agg, 0, N);
        k_gemm<<<mm_blocks, 256, 0, stream>>>(
            hin, packAll + (size_t)(2 * l + 1) * 49152,
            bias + l * DD, agg, 1, N);
        k_ln<<<ln_blocks, 256, 0, stream>>>(
            agg, (l < L - 1) ? hb : (unsigned short*)nullptr,
            lng + l * DD, lnb + l * DD, alpha + l, N);
        hin = agg;
    }
    k_cls<<<mm_blocks, 256, 0, stream>>>(hin, packAll + (size_t)(2 * L) * 49152,
                                         b1, clng, clnb, W2, b2,
                                         (float*)d_out, N);
}

// Round 8
// 803.399 us; speedup vs baseline: 1.2535x; 1.0928x over previous
//
#include <hip/hip_runtime.h>
#include <math.h>

#define DD 128
#define SPB 400   // nodes per permute bucket
#define CBM 128   // rows per block in MFMA GEMM kernels

using fragT = __attribute__((ext_vector_type(8))) short;   // 8 bf16
using f32x4 = __attribute__((ext_vector_type(4))) float;

__device__ inline float trunc_bf16(float a) {
    return __uint_as_float(__float_as_uint(a) & 0xFFFF0000u);
}
__device__ inline short bf16bits(float a) {
    return (short)(__float_as_uint(a) >> 16);
}
__device__ inline unsigned short bf16rne(float f) {   // round-to-nearest-even
    unsigned int u = __float_as_uint(f);
    return (unsigned short)((u + 0x7FFFu + ((u >> 16) & 1u)) >> 16);
}
__device__ inline float b2f(unsigned short u) {
    return __uint_as_float((unsigned int)u << 16);
}
// Exact 3-way bf16 split: x = f1 + f2 + f3
__device__ inline void split8_3(const float4 v0, const float4 v1,
                                fragT& f1, fragT& f2, fragT& f3) {
    const float x[8] = {v0.x, v0.y, v0.z, v0.w, v1.x, v1.y, v1.z, v1.w};
    #pragma unroll
    for (int j = 0; j < 8; ++j) {
        const float a  = x[j];
        const float t1 = trunc_bf16(a);
        const float r1 = a - t1;
        const float t2 = trunc_bf16(r1);
        const float r2 = r1 - t2;
        f1[j] = bf16bits(a);
        f2[j] = bf16bits(t2);
        f3[j] = bf16bits(r2);
    }
}

// ===========================================================================
// Pack a 128x128 fp32 W ([K][N] row-major) into MFMA-frag order, 3-way split.
// Per 64-K chunk c: [comp(3)][s(2)][t(8)][lane(64)][j(8)] shorts (24576/chunk)
//   k = c*64 + s*32 + (lane>>4)*8 + j ;  n = t*16 + (lane&15)
// (proven; 7 launches.)
// ===========================================================================
__global__ __launch_bounds__(64) void k_pack_cls(
    const float* __restrict__ W, short* __restrict__ packC)
{
    const int b = blockIdx.x;              // 32 blocks
    const int c = b >> 4, s = (b >> 3) & 1, t = b & 7;
    const int l = threadIdx.x;
    const int kg = c * 64 + s * 32 + ((l >> 4) << 3);
    const int n  = t * 16 + (l & 15);
    fragT c1, c2, c3;
    #pragma unroll
    for (int j = 0; j < 8; ++j) {
        const float a  = W[(kg + j) * DD + n];
        const float t1 = trunc_bf16(a);
        const float r1 = a - t1;
        const float t2 = trunc_bf16(r1);
        const float r2 = r1 - t2;
        c1[j] = bf16bits(a);
        c2[j] = bf16bits(t2);
        c3[j] = bf16bits(r2);
    }
    short* base = packC + (size_t)c * 24576 + s * 4096 + t * 512 + l * 8;
    *(fragT*)(base)         = c1;
    *(fragT*)(base + 8192)  = c2;
    *(fragT*)(base + 16384) = c3;
}

// ===========================================================================
// One-time fp32 -> bf16 (RNE) conversion of features.
// ===========================================================================
__global__ __launch_bounds__(256) void k_tobf16(
    const float* __restrict__ in, unsigned short* __restrict__ out, int n4)
{
    int i = blockIdx.x * 256 + threadIdx.x;
    if (i < n4) {
        const float4 v = ((const float4*)in)[i];
        ushort4 o;
        o.x = bf16rne(v.x); o.y = bf16rne(v.y);
        o.z = bf16rne(v.z); o.w = bf16rne(v.w);
        ((ushort4*)out)[i] = o;
    }
}

// ===========================================================================
// Stage 1 (once per call): counting-sort edges by dst -> CSR
// ===========================================================================
__global__ __launch_bounds__(256) void k_hist(
    const int* __restrict__ dst, int* __restrict__ counts, int E)
{
    int e = blockIdx.x * 256 + threadIdx.x;
    if (e < E) atomicAdd(&counts[dst[e]], 1);
}

__global__ __launch_bounds__(256) void k_scan1(
    const int* cnt, int* excl, int* __restrict__ bsum, int N)
{
    __shared__ int tmp[256];
    const int t = threadIdx.x;
    const int base = blockIdx.x * 1024 + t * 4;
    int v[4];
    #pragma unroll
    for (int i = 0; i < 4; ++i) v[i] = (base + i < N) ? cnt[base + i] : 0;
    const int s = v[0] + v[1] + v[2] + v[3];
    tmp[t] = s;
    __syncthreads();
    int val = s;
    for (int off = 1; off < 256; off <<= 1) {
        int u = (t >= off) ? tmp[t - off] : 0;
        __syncthreads();
        val += u;
        tmp[t] = val;
        __syncthreads();
    }
    int run = val - s;
    #pragma unroll
    for (int i = 0; i < 4; ++i) {
        if (base + i < N) excl[base + i] = run;
        run += v[i];
    }
    if (t == 255) bsum[blockIdx.x] = val;
}

__global__ __launch_bounds__(256) void k_scan2(int* __restrict__ bsum, int nb)
{
    __shared__ int tmp[256];
    const int t = threadIdx.x;
    const int s = (t < nb) ? bsum[t] : 0;
    tmp[t] = s;
    __syncthreads();
    int val = s;
    for (int off = 1; off < 256; off <<= 1) {
        int u = (t >= off) ? tmp[t - off] : 0;
        __syncthreads();
        val += u;
        tmp[t] = val;
        __syncthreads();
    }
    if (t < nb) bsum[t] = val - s;
}

__global__ __launch_bounds__(256) void k_scan3(
    const int* __restrict__ excl, const int* __restrict__ bsum,
    int* __restrict__ starts, int* __restrict__ cursor1, int N, int E)
{
    int i = blockIdx.x * 256 + threadIdx.x;
    if (i < N) {
        int v = excl[i] + bsum[i >> 10];
        starts[i] = v;
        if (i % SPB == 0) cursor1[i / SPB] = v;
        if (i == N - 1) starts[N] = E;
    }
}

// Permute pass 1: coarse-bucket (dst/SPB) with LDS histogram; grouped writes.
__global__ __launch_bounds__(256) void k_bucket(
    const int* __restrict__ src, const int* __restrict__ dst,
    const float* __restrict__ ew, int* __restrict__ cursor1,
    int4* __restrict__ tmp, int E)
{
    __shared__ int hist[256];
    __shared__ int base[256];
    const int t = threadIdx.x;
    const int e0 = blockIdx.x * 2048;
    hist[t] = 0;
    __syncthreads();
    int myb[8], myr[8];
    #pragma unroll
    for (int u = 0; u < 8; ++u) {
        int e = e0 + u * 256 + t;
        if (e < E) {
            int b = dst[e] / SPB;
            myb[u] = b;
            myr[u] = atomicAdd(&hist[b], 1);
        } else myb[u] = -1;
    }
    __syncthreads();
    if (hist[t] > 0) base[t] = atomicAdd(&cursor1[t], hist[t]);
    __syncthreads();
    #pragma unroll
    for (int u = 0; u < 8; ++u) {
        int e = e0 + u * 256 + t;
        if (e < E)
            tmp[base[myb[u]] + myr[u]] =
                make_int4(src[e], dst[e], __float_as_int(ew[e]), 0);
    }
}

// Permute pass 2: one block per bucket; LDS cursors; L2-local placement.
__global__ __launch_bounds__(256) void k_place(
    const int4* __restrict__ tmp, const int* __restrict__ starts,
    int2* __restrict__ edges_s, int N, int E)
{
    __shared__ int cur[SPB];
    const int b  = blockIdx.x;
    const int n0 = b * SPB;
    const int n1 = min(N, n0 + SPB);
    const int t  = threadIdx.x;
    for (int i = t; i < n1 - n0; i += 256) cur[i] = starts[n0 + i];
    __syncthreads();
    const int r0 = starts[n0];
    const int r1 = (n1 < N) ? starts[n1] : E;
    for (int e = r0 + t; e < r1; e += 256) {
        int4 rec = tmp[e];
        int pos = atomicAdd(&cur[rec.y - n0], 1);
        edges_s[pos] = make_int2(rec.x, rec.z);
    }
}

// ===========================================================================
// Gather segment-sum from BF16 h (R7-proven, byte-identical).
// ===========================================================================
__global__ __launch_bounds__(256) void k_gather_bf16(
    const unsigned short* __restrict__ hb, const int* __restrict__ starts,
    const int2* __restrict__ edges, float* __restrict__ agg, int N)
{
    const int w = (blockIdx.x * 256 + threadIdx.x) >> 6;
    if (w >= N) return;
    const int lane = threadIdx.x & 63;
    const int half = lane >> 5;
    const int c4   = (lane & 31) << 2;
    const int s0 = starts[w];
    const int s1 = starts[w + 1];
    float4 a0 = make_float4(0.f, 0.f, 0.f, 0.f);
    float4 a1 = make_float4(0.f, 0.f, 0.f, 0.f);
    int j = s0;
    for (; j + 8 <= s1; j += 8) {
        const int2 eA = edges[j     + half];
        const int2 eB = edges[j + 2 + half];
        const int2 eC = edges[j + 4 + half];
        const int2 eD = edges[j + 6 + half];
        const ushort4 vA = *(const ushort4*)(hb + (size_t)eA.x * DD + c4);
        const ushort4 vB = *(const ushort4*)(hb + (size_t)eB.x * DD + c4);
        const ushort4 vC = *(const ushort4*)(hb + (size_t)eC.x * DD + c4);
        const ushort4 vD = *(const ushort4*)(hb + (size_t)eD.x * DD + c4);
        const float wA = __int_as_float(eA.y), wB = __int_as_float(eB.y);
        const float wC = __int_as_float(eC.y), wD = __int_as_float(eD.y);
        a0.x = fmaf(b2f(vA.x), wA, a0.x); a0.y = fmaf(b2f(vA.y), wA, a0.y);
        a0.z = fmaf(b2f(vA.z), wA, a0.z); a0.w = fmaf(b2f(vA.w), wA, a0.w);
        a1.x = fmaf(b2f(vB.x), wB, a1.x); a1.y = fmaf(b2f(vB.y), wB, a1.y);
        a1.z = fmaf(b2f(vB.z), wB, a1.z); a1.w = fmaf(b2f(vB.w), wB, a1.w);
        a0.x = fmaf(b2f(vC.x), wC, a0.x); a0.y = fmaf(b2f(vC.y), wC, a0.y);
        a0.z = fmaf(b2f(vC.z), wC, a0.z); a0.w = fmaf(b2f(vC.w), wC, a0.w);
        a1.x = fmaf(b2f(vD.x), wD, a1.x); a1.y = fmaf(b2f(vD.y), wD, a1.y);
        a1.z = fmaf(b2f(vD.z), wD, a1.z); a1.w = fmaf(b2f(vD.w), wD, a1.w);
    }
    for (; j < s1; j += 2) {
        const int idx = j + half;
        const bool ok = idx < s1;
        const int2 e = edges[ok ? idx : s1 - 1];
        const float wt = ok ? __int_as_float(e.y) : 0.f;
        const ushort4 v = *(const ushort4*)(hb + (size_t)e.x * DD + c4);
        a0.x = fmaf(b2f(v.x), wt, a0.x); a0.y = fmaf(b2f(v.y), wt, a0.y);
        a0.z = fmaf(b2f(v.z), wt, a0.z); a0.w = fmaf(b2f(v.w), wt, a0.w);
    }
    float4 tot = make_float4(a0.x + a1.x, a0.y + a1.y, a0.z + a1.z, a0.w + a1.w);
    float4 oth;
    oth.x = __shfl_xor(tot.x, 32);
    oth.y = __shfl_xor(tot.y, 32);
    oth.z = __shfl_xor(tot.z, 32);
    oth.w = __shfl_xor(tot.w, 32);
    if (half == 0) {
        tot.x += oth.x; tot.y += oth.y; tot.z += oth.z; tot.w += oth.w;
        *(float4*)(agg + (size_t)w * DD + c4) = tot;
    }
}

// ===========================================================================
// FUSED dual-source MFMA GEMM:  X = agg @ Wrel + hin @ Wroot + bias.
// 4 LDS stages: (Wrel,c0),(Wrel,c1),(Wroot,c0),(Wroot,c1) -- each stages a
// 48 KB pre-packed chunk and accumulates into the same acc (R1's staging
// sequence; epilogue is R4's PROVEN trivial +bias store -- NO fused LN).
// BISECT: if this fails, the 4-stage dual-source core is the historic bug;
// if it passes, the fused-LN epilogue was.
// X aliases agg: block reads only its own 128 rows (stages 0-1), all reads
// precede the epilogue stores; hin is a disjoint buffer.
// ===========================================================================
__global__ __launch_bounds__(256, 3) void k_gemm2(
    const float* agg, const float* __restrict__ hin,
    const short* __restrict__ packRel, const short* __restrict__ packRoot,
    const float* __restrict__ bias, float* X, int N)
{
    __shared__ short sB[24576];   // one 64-K chunk, 3 components, 48 KB

    const int t256 = threadIdx.x;
    const int lane = t256 & 63;
    const int w    = t256 >> 6;
    const int q    = lane >> 4;
    const int r16  = lane & 15;
    const int rowbase = blockIdx.x * CBM + w * 32;

    f32x4 acc[2][8];
    #pragma unroll
    for (int mt = 0; mt < 2; ++mt)
        #pragma unroll
        for (int t = 0; t < 8; ++t) acc[mt][t] = (f32x4)(0.f);

    for (int stage = 0; stage < 4; ++stage) {
        const float* A  = (stage < 2) ? agg : hin;
        const short* pk = ((stage < 2) ? packRel : packRoot)
                          + (size_t)(stage & 1) * 24576;
        const int kb = (stage & 1) * 64;
        if (stage) __syncthreads();
        {   // copy 48 KB pre-packed chunk (3072 uint4)
            const uint4* srcp = (const uint4*)pk;
            uint4* dstp = (uint4*)sB;
            #pragma unroll
            for (int i = 0; i < 12; ++i)
                dstp[i * 256 + t256] = srcp[i * 256 + t256];
        }
        __syncthreads();

        #pragma unroll
        for (int s = 0; s < 2; ++s) {
            const int kq = kb + s * 32 + q * 8;
            fragT a1[2], a2[2], a3[2];
            #pragma unroll
            for (int mt = 0; mt < 2; ++mt) {
                const int row = rowbase + mt * 16 + r16;
                float4 v0 = make_float4(0.f, 0.f, 0.f, 0.f);
                float4 v1 = make_float4(0.f, 0.f, 0.f, 0.f);
                if (row < N) {
                    v0 = *(const float4*)(A + (size_t)row * DD + kq);
                    v1 = *(const float4*)(A + (size_t)row * DD + kq + 4);
                }
                split8_3(v0, v1, a1[mt], a2[mt], a3[mt]);
            }
            const short* sbase = sB + s * 4096 + lane * 8;
            #pragma unroll
            for (int t = 0; t < 8; ++t) {
                const fragT b1c = *(const fragT*)(sbase + t * 512);
                const fragT b2c = *(const fragT*)(sbase + 8192 + t * 512);
                const fragT b3c = *(const fragT*)(sbase + 16384 + t * 512);
                #pragma unroll
                for (int mt = 0; mt < 2; ++mt) {
                    acc[mt][t] = __builtin_amdgcn_mfma_f32_16x16x32_bf16(a1[mt], b1c, acc[mt][t], 0, 0, 0);
                    acc[mt][t] = __builtin_amdgcn_mfma_f32_16x16x32_bf16(a2[mt], b1c, acc[mt][t], 0, 0, 0);
                    acc[mt][t] = __builtin_amdgcn_mfma_f32_16x16x32_bf16(a1[mt], b2c, acc[mt][t], 0, 0, 0);
                    acc[mt][t] = __builtin_amdgcn_mfma_f32_16x16x32_bf16(a3[mt], b1c, acc[mt][t], 0, 0, 0);
                    acc[mt][t] = __builtin_amdgcn_mfma_f32_16x16x32_bf16(a2[mt], b2c, acc[mt][t], 0, 0, 0);
                    acc[mt][t] = __builtin_amdgcn_mfma_f32_16x16x32_bf16(a1[mt], b3c, acc[mt][t], 0, 0, 0);
                }
            }
        }
    }

    // epilogue (R4-proven trivial form): X[row][col] = acc + bias[col]
    #pragma unroll
    for (int mt = 0; mt < 2; ++mt) {
        #pragma unroll
        for (int r = 0; r < 4; ++r) {
            const int row = rowbase + mt * 16 + q * 4 + r;
            if (row < N) {
                #pragma unroll
                for (int t = 0; t < 8; ++t) {
                    const int col = t * 16 + r16;
                    X[(size_t)row * DD + col] = acc[mt][t][r] + bias[col];
                }
            }
        }
    }
}

// ===========================================================================
// In-place row LayerNorm + PReLU on X [N x 128], fp32 exact; additionally
// emits a bf16(RNE) copy into hb when hb != 0. (R7-proven, byte-identical.)
// ===========================================================================
__global__ __launch_bounds__(256) void k_ln(
    float* X, unsigned short* hb,
    const float* __restrict__ lng, const float* __restrict__ lnb,
    const float* __restrict__ alpha_p, int N)
{
    const int row = blockIdx.x * 4 + (threadIdx.x >> 6);
    if (row >= N) return;
    const int lane = threadIdx.x & 63;
    float2 v = *(float2*)(X + (size_t)row * DD + lane * 2);
    float s  = v.x + v.y;
    float s2 = fmaf(v.x, v.x, v.y * v.y);
    #pragma unroll
    for (int off = 32; off > 0; off >>= 1) {
        s  += __shfl_xor(s,  off, 64);
        s2 += __shfl_xor(s2, off, 64);
    }
    const float mean = s * (1.f / 128.f);
    float var = s2 * (1.f / 128.f) - mean * mean;
    var = var < 0.f ? 0.f : var;
    const float rstd = rsqrtf(var + 1e-5f);
    const float2 g = *(const float2*)(lng + lane * 2);
    const float2 b = *(const float2*)(lnb + lane * 2);
    const float alpha = alpha_p[0];
    float y0 = (v.x - mean) * rstd * g.x + b.x;
    float y1 = (v.y - mean) * rstd * g.y + b.y;
    y0 = (y0 >= 0.f) ? y0 : alpha * y0;
    y1 = (y1 >= 0.f) ? y1 : alpha * y1;
    *(float2*)(X + (size_t)row * DD + lane * 2) = make_float2(y0, y1);
    if (hb) {
        ushort2 hv;
        hv.x = bf16rne(y0);
        hv.y = bf16rne(y1);
        *(ushort2*)(hb + (size_t)row * DD + lane * 2) = hv;
    }
}

// ===========================================================================
// Classifier (MFMA): logits = LN(relu(h @ W1 + b1)) @ W2 + b2
// (proven, byte-identical.)
// ===========================================================================
__global__ __launch_bounds__(256, 3) void k_cls(
    const float* __restrict__ hin, const short* __restrict__ packC,
    const float* __restrict__ b1, const float* __restrict__ lng,
    const float* __restrict__ lnb, const float* __restrict__ W2,
    const float* __restrict__ b2, float* __restrict__ out, int N)
{
    __shared__ short sB[24576];   // one 64-K chunk, 3 components, 48 KB

    const int t256 = threadIdx.x;
    const int lane = t256 & 63;
    const int w    = t256 >> 6;
    const int q    = lane >> 4;
    const int r16  = lane & 15;
    const int rowbase = blockIdx.x * CBM + w * 32;

    f32x4 acc[2][8];
    #pragma unroll
    for (int mt = 0; mt < 2; ++mt)
        #pragma unroll
        for (int t = 0; t < 8; ++t) acc[mt][t] = (f32x4)(0.f);

    for (int c = 0; c < 2; ++c) {
        if (c) __syncthreads();
        {   // copy 48 KB pre-packed chunk (3072 uint4)
            const uint4* srcp = (const uint4*)(packC + (size_t)c * 24576);
            uint4* dstp = (uint4*)sB;
            #pragma unroll
            for (int i = 0; i < 12; ++i)
                dstp[i * 256 + t256] = srcp[i * 256 + t256];
        }
        __syncthreads();

        const int kb = c * 64;
        #pragma unroll
        for (int s = 0; s < 2; ++s) {
            const int kq = kb + s * 32 + q * 8;
            fragT a1[2], a2[2], a3[2];
            #pragma unroll
            for (int mt = 0; mt < 2; ++mt) {
                const int row = rowbase + mt * 16 + r16;
                float4 v0 = make_float4(0.f, 0.f, 0.f, 0.f);
                float4 v1 = make_float4(0.f, 0.f, 0.f, 0.f);
                if (row < N) {
                    v0 = *(const float4*)(hin + (size_t)row * DD + kq);
                    v1 = *(const float4*)(hin + (size_t)row * DD + kq + 4);
                }
                split8_3(v0, v1, a1[mt], a2[mt], a3[mt]);
            }
            const short* sbase = sB + s * 4096 + lane * 8;
            #pragma unroll
            for (int t = 0; t < 8; ++t) {
                const fragT b1c = *(const fragT*)(sbase + t * 512);
                const fragT b2c = *(const fragT*)(sbase + 8192 + t * 512);
                const fragT b3c = *(const fragT*)(sbase + 16384 + t * 512);
                #pragma unroll
                for (int mt = 0; mt < 2; ++mt) {
                    acc[mt][t] = __builtin_amdgcn_mfma_f32_16x16x32_bf16(a1[mt], b1c, acc[mt][t], 0, 0, 0);
                    acc[mt][t] = __builtin_amdgcn_mfma_f32_16x16x32_bf16(a2[mt], b1c, acc[mt][t], 0, 0, 0);
                    acc[mt][t] = __builtin_amdgcn_mfma_f32_16x16x32_bf16(a1[mt], b2c, acc[mt][t], 0, 0, 0);
                    acc[mt][t] = __builtin_amdgcn_mfma_f32_16x16x32_bf16(a3[mt], b1c, acc[mt][t], 0, 0, 0);
                    acc[mt][t] = __builtin_amdgcn_mfma_f32_16x16x32_bf16(a2[mt], b2c, acc[mt][t], 0, 0, 0);
                    acc[mt][t] = __builtin_amdgcn_mfma_f32_16x16x32_bf16(a1[mt], b3c, acc[mt][t], 0, 0, 0);
                }
            }
        }
    }

    float b1v[8], gvv[8], bvv[8], w2c0[8], w2c1[8];
    #pragma unroll
    for (int t = 0; t < 8; ++t) {
        const int col = t * 16 + r16;
        b1v[t] = b1[col]; gvv[t] = lng[col]; bvv[t] = lnb[col];
        const float2 w2 = *(const float2*)(W2 + col * 2);
        w2c0[t] = w2.x; w2c1[t] = w2.y;
    }
    const float b2v0 = b2[0], b2v1 = b2[1];

    #pragma unroll
    for (int mt = 0; mt < 2; ++mt) {
        #pragma unroll
        for (int r = 0; r < 4; ++r) {
            const int row = rowbase + mt * 16 + q * 4 + r;
            float xv[8];
            float s = 0.f, s2 = 0.f;
            #pragma unroll
            for (int t = 0; t < 8; ++t) {
                float x = acc[mt][t][r] + b1v[t];
                x = x > 0.f ? x : 0.f;      // relu
                xv[t] = x; s += x; s2 = fmaf(x, x, s2);
            }
            #pragma unroll
            for (int off = 8; off > 0; off >>= 1) {
                s  += __shfl_xor(s,  off, 16);
                s2 += __shfl_xor(s2, off, 16);
            }
            const float mean = s * (1.f / 128.f);
            float var = s2 * (1.f / 128.f) - mean * mean;
            var = var < 0.f ? 0.f : var;
            const float rstd = rsqrtf(var + 1e-5f);
            float p0 = 0.f, p1 = 0.f;
            #pragma unroll
            for (int t = 0; t < 8; ++t) {
                const float z = (xv[t] - mean) * rstd * gvv[t] + bvv[t];
                p0 = fmaf(z, w2c0[t], p0);
                p1 = fmaf(z, w2c1[t], p1);
            }
            #pragma unroll
            for (int off = 8; off > 0; off >>= 1) {
                p0 += __shfl_xor(p0, off, 16);
                p1 += __shfl_xor(p1, off, 16);
            }
            if (r16 == 0 && row < N) {
                out[row * 2 + 0] = p0 + b2v0;
                out[row * 2 + 1] = p1 + b2v1;
            }
        }
    }
}

// ===========================================================================
extern "C" void kernel_launch(void* const* d_in, const int* in_sizes, int n_in,
                              void* d_out, int out_size, void* d_ws, size_t ws_size,
                              hipStream_t stream) {
    const float* features = (const float*)d_in[0];
    const int*   eidx     = (const int*)  d_in[1];
    const float* ew       = (const float*)d_in[2];
    const float* Wrel     = (const float*)d_in[3];
    const float* Wroot    = (const float*)d_in[4];
    const float* bias     = (const float*)d_in[5];
    const float* lng      = (const float*)d_in[6];
    const float* lnb      = (const float*)d_in[7];
    const float* alpha    = (const float*)d_in[8];
    const float* W1       = (const float*)d_in[9];
    const float* b1       = (const float*)d_in[10];
    const float* clng     = (const float*)d_in[11];
    const float* clnb     = (const float*)d_in[12];
    const float* W2       = (const float*)d_in[13];
    const float* b2       = (const float*)d_in[14];

    const int N = in_sizes[0] / DD;
    const int E = in_sizes[2];
    const int L = in_sizes[8];

    // workspace (~142.3 MB of >=155 MB)
    float* bufA    = (float*)d_ws;                   // N*128 f
    float* bufB    = bufA + (size_t)N * DD;          // N*128 f
    int2*  edges_s = (int2*)(bufB + (size_t)N * DD); // E
    int*   counts  = (int*)(edges_s + E);            // N (scanned in-place)
    int*   starts  = counts + N;                     // N+1 (pristine + sentinel)
    int*   bsum    = starts + N + 1;                 // 258
    int*   cursor1 = bsum + 258;                     // 256 (+2 pad)
    unsigned short* hb = (unsigned short*)(cursor1 + 261);  // N*128 bf16, 16B-aligned
    short* packAll = (short*)(hb + (size_t)N * DD);  // (2L+1)*49152 shorts
    int4*  tmp     = (int4*)bufA;                    // E recs, dead before layers

    const int* src = eidx;
    const int* dst = eidx + E;

    const int eb      = (E + 255) / 256;
    const int eb2k    = (E + 2047) / 2048;
    const int nb      = (N + 1023) / 1024;
    const int NBk     = (N + SPB - 1) / SPB;
    const int mm_blocks  = (N + CBM - 1) / CBM;
    const int ln_blocks  = (N + 3) / 4;
    const int ga_blocks  = (N * 64 + 255) / 256;
    const int cv_blocks  = (N * DD / 4 + 255) / 256;

    // ---- pack all weight matrices (W_rel[l], W_root[l], cls W1) ----
    for (int l = 0; l < L; ++l) {
        k_pack_cls<<<32, 64, 0, stream>>>(Wrel  + (size_t)l * DD * DD,
                                          packAll + (size_t)(2 * l)     * 49152);
        k_pack_cls<<<32, 64, 0, stream>>>(Wroot + (size_t)l * DD * DD,
                                          packAll + (size_t)(2 * l + 1) * 49152);
    }
    k_pack_cls<<<32, 64, 0, stream>>>(W1, packAll + (size_t)(2 * L) * 49152);

    // ---- features -> bf16 (for layer-0 gather) ----
    k_tobf16<<<cv_blocks, 256, 0, stream>>>(features, hb, N * DD / 4);

    // ---- build CSR by dst (once per call) ----
    hipMemsetAsync(counts, 0, (size_t)N * sizeof(int), stream);
    k_hist  <<<eb, 256, 0, stream>>>(dst, counts, E);
    k_scan1 <<<nb, 256, 0, stream>>>(counts, counts, bsum, N);   // in-place
    k_scan2 <<<1,  256, 0, stream>>>(bsum, nb);
    k_scan3 <<<(N + 255) / 256, 256, 0, stream>>>(counts, bsum, starts, cursor1, N, E);
    k_bucket<<<eb2k, 256, 0, stream>>>(src, dst, ew, cursor1, tmp, E);
    k_place <<<NBk, 256, 0, stream>>>(tmp, starts, edges_s, N, E);

    // ---- layers: gather(bf16) -> fused GEMM2(+bias) -> LN(+bf16 copy) ----
    const float* hin = features;
    for (int l = 0; l < L; ++l) {
        float* agg = (l & 1) ? bufB : bufA;   // X aliases agg (block-local safe)
        k_gather_bf16<<<ga_blocks, 256, 0, stream>>>(hb, starts, edges_s, agg, N);
        k_gemm2<<<mm_blocks, 256, 0, stream>>>(
            agg, hin,
            packAll + (size_t)(2 * l)     * 49152,
            packAll + (size_t)(2 * l + 1) * 49152,
            bias + l * DD, agg, N);
        k_ln<<<ln_blocks, 256, 0, stream>>>(
            agg, (l < L - 1) ? hb : (unsigned short*)nullptr,
            lng + l * DD, lnb + l * DD, alpha + l, N);
        hin = agg;
    }
    k_cls<<<mm_blocks, 256, 0, stream>>>(hin, packAll + (size_t)(2 * L) * 49152,
                                         b1, clng, clnb, W2, b2,
                                         (float*)d_out, N);
}

// Round 9
// 680.052 us; speedup vs baseline: 1.4808x; 1.1814x over previous
//
#include <hip/hip_runtime.h>
#include <math.h>

#define DD 128
#define SPB 400   // nodes per permute bucket
#define CBM 128   // rows per block in MFMA GEMM kernels

using fragT = __attribute__((ext_vector_type(8))) short;   // 8 bf16
using f32x4 = __attribute__((ext_vector_type(4))) float;

__device__ inline float trunc_bf16(float a) {
    return __uint_as_float(__float_as_uint(a) & 0xFFFF0000u);
}
__device__ inline short bf16bits(float a) {
    return (short)(__float_as_uint(a) >> 16);
}
__device__ inline unsigned short bf16rne(float f) {   // round-to-nearest-even
    unsigned int u = __float_as_uint(f);
    return (unsigned short)((u + 0x7FFFu + ((u >> 16) & 1u)) >> 16);
}
__device__ inline float b2f(unsigned short u) {
    return __uint_as_float((unsigned int)u << 16);
}
// Exact 3-way bf16 split: x = f1 + f2 + f3
__device__ inline void split8_3(const float4 v0, const float4 v1,
                                fragT& f1, fragT& f2, fragT& f3) {
    const float x[8] = {v0.x, v0.y, v0.z, v0.w, v1.x, v1.y, v1.z, v1.w};
    #pragma unroll
    for (int j = 0; j < 8; ++j) {
        const float a  = x[j];
        const float t1 = trunc_bf16(a);
        const float r1 = a - t1;
        const float t2 = trunc_bf16(r1);
        const float r2 = r1 - t2;
        f1[j] = bf16bits(a);
        f2[j] = bf16bits(t2);
        f3[j] = bf16bits(r2);
    }
}

// ===========================================================================
// Pack a 128x128 fp32 W ([K][N] row-major) into MFMA-frag order, 3-way split.
// Per 64-K chunk c: [comp(3)][s(2)][t(8)][lane(64)][j(8)] shorts (24576/chunk)
//   k = c*64 + s*32 + (lane>>4)*8 + j ;  n = t*16 + (lane&15)
// (proven; 7 launches.)
// ===========================================================================
__global__ __launch_bounds__(64) void k_pack_cls(
    const float* __restrict__ W, short* __restrict__ packC)
{
    const int b = blockIdx.x;              // 32 blocks
    const int c = b >> 4, s = (b >> 3) & 1, t = b & 7;
    const int l = threadIdx.x;
    const int kg = c * 64 + s * 32 + ((l >> 4) << 3);
    const int n  = t * 16 + (l & 15);
    fragT c1, c2, c3;
    #pragma unroll
    for (int j = 0; j < 8; ++j) {
        const float a  = W[(kg + j) * DD + n];
        const float t1 = trunc_bf16(a);
        const float r1 = a - t1;
        const float t2 = trunc_bf16(r1);
        const float r2 = r1 - t2;
        c1[j] = bf16bits(a);
        c2[j] = bf16bits(t2);
        c3[j] = bf16bits(r2);
    }
    short* base = packC + (size_t)c * 24576 + s * 4096 + t * 512 + l * 8;
    *(fragT*)(base)         = c1;
    *(fragT*)(base + 8192)  = c2;
    *(fragT*)(base + 16384) = c3;
}

// ===========================================================================
// One-time fp32 -> bf16 (RNE) conversion of features.
// ===========================================================================
__global__ __launch_bounds__(256) void k_tobf16(
    const float* __restrict__ in, unsigned short* __restrict__ out, int n4)
{
    int i = blockIdx.x * 256 + threadIdx.x;
    if (i < n4) {
        const float4 v = ((const float4*)in)[i];
        ushort4 o;
        o.x = bf16rne(v.x); o.y = bf16rne(v.y);
        o.z = bf16rne(v.z); o.w = bf16rne(v.w);
        ((ushort4*)out)[i] = o;
    }
}

// ===========================================================================
// Stage 1 (once per call): counting-sort edges by dst -> CSR
// ===========================================================================
__global__ __launch_bounds__(256) void k_hist(
    const int* __restrict__ dst, int* __restrict__ counts, int E)
{
    int e = blockIdx.x * 256 + threadIdx.x;
    if (e < E) atomicAdd(&counts[dst[e]], 1);
}

__global__ __launch_bounds__(256) void k_scan1(
    const int* cnt, int* excl, int* __restrict__ bsum, int N)
{
    __shared__ int tmp[256];
    const int t = threadIdx.x;
    const int base = blockIdx.x * 1024 + t * 4;
    int v[4];
    #pragma unroll
    for (int i = 0; i < 4; ++i) v[i] = (base + i < N) ? cnt[base + i] : 0;
    const int s = v[0] + v[1] + v[2] + v[3];
    tmp[t] = s;
    __syncthreads();
    int val = s;
    for (int off = 1; off < 256; off <<= 1) {
        int u = (t >= off) ? tmp[t - off] : 0;
        __syncthreads();
        val += u;
        tmp[t] = val;
        __syncthreads();
    }
    int run = val - s;
    #pragma unroll
    for (int i = 0; i < 4; ++i) {
        if (base + i < N) excl[base + i] = run;
        run += v[i];
    }
    if (t == 255) bsum[blockIdx.x] = val;
}

__global__ __launch_bounds__(256) void k_scan2(int* __restrict__ bsum, int nb)
{
    __shared__ int tmp[256];
    const int t = threadIdx.x;
    const int s = (t < nb) ? bsum[t] : 0;
    tmp[t] = s;
    __syncthreads();
    int val = s;
    for (int off = 1; off < 256; off <<= 1) {
        int u = (t >= off) ? tmp[t - off] : 0;
        __syncthreads();
        val += u;
        tmp[t] = val;
        __syncthreads();
    }
    if (t < nb) bsum[t] = val - s;
}

__global__ __launch_bounds__(256) void k_scan3(
    const int* __restrict__ excl, const int* __restrict__ bsum,
    int* __restrict__ starts, int* __restrict__ cursor1, int N, int E)
{
    int i = blockIdx.x * 256 + threadIdx.x;
    if (i < N) {
        int v = excl[i] + bsum[i >> 10];
        starts[i] = v;
        if (i % SPB == 0) cursor1[i / SPB] = v;
        if (i == N - 1) starts[N] = E;
    }
}

// Permute pass 1: coarse-bucket (dst/SPB) with LDS histogram; grouped writes.
__global__ __launch_bounds__(256) void k_bucket(
    const int* __restrict__ src, const int* __restrict__ dst,
    const float* __restrict__ ew, int* __restrict__ cursor1,
    int4* __restrict__ tmp, int E)
{
    __shared__ int hist[256];
    __shared__ int base[256];
    const int t = threadIdx.x;
    const int e0 = blockIdx.x * 2048;
    hist[t] = 0;
    __syncthreads();
    int myb[8], myr[8];
    #pragma unroll
    for (int u = 0; u < 8; ++u) {
        int e = e0 + u * 256 + t;
        if (e < E) {
            int b = dst[e] / SPB;
            myb[u] = b;
            myr[u] = atomicAdd(&hist[b], 1);
        } else myb[u] = -1;
    }
    __syncthreads();
    if (hist[t] > 0) base[t] = atomicAdd(&cursor1[t], hist[t]);
    __syncthreads();
    #pragma unroll
    for (int u = 0; u < 8; ++u) {
        int e = e0 + u * 256 + t;
        if (e < E)
            tmp[base[myb[u]] + myr[u]] =
                make_int4(src[e], dst[e], __float_as_int(ew[e]), 0);
    }
}

// Permute pass 2: one block per bucket; LDS cursors; L2-local placement.
__global__ __launch_bounds__(256) void k_place(
    const int4* __restrict__ tmp, const int* __restrict__ starts,
    int2* __restrict__ edges_s, int N, int E)
{
    __shared__ int cur[SPB];
    const int b  = blockIdx.x;
    const int n0 = b * SPB;
    const int n1 = min(N, n0 + SPB);
    const int t  = threadIdx.x;
    for (int i = t; i < n1 - n0; i += 256) cur[i] = starts[n0 + i];
    __syncthreads();
    const int r0 = starts[n0];
    const int r1 = (n1 < N) ? starts[n1] : E;
    for (int e = r0 + t; e < r1; e += 256) {
        int4 rec = tmp[e];
        int pos = atomicAdd(&cur[rec.y - n0], 1);
        edges_s[pos] = make_int2(rec.x, rec.z);
    }
}

// ===========================================================================
// Gather segment-sum from BF16 h; OUTPUT IS NOW BF16 (aggb) -- halves the
// agg write traffic and lets the GEMM consume it as a raw MFMA fragment.
// fp32 accumulation internally (unchanged).
// ===========================================================================
__global__ __launch_bounds__(256) void k_gather_bf16(
    const unsigned short* __restrict__ hb, const int* __restrict__ starts,
    const int2* __restrict__ edges, unsigned short* __restrict__ aggb, int N)
{
    const int w = (blockIdx.x * 256 + threadIdx.x) >> 6;
    if (w >= N) return;
    const int lane = threadIdx.x & 63;
    const int half = lane >> 5;
    const int c4   = (lane & 31) << 2;
    const int s0 = starts[w];
    const int s1 = starts[w + 1];
    float4 a0 = make_float4(0.f, 0.f, 0.f, 0.f);
    float4 a1 = make_float4(0.f, 0.f, 0.f, 0.f);
    int j = s0;
    for (; j + 8 <= s1; j += 8) {
        const int2 eA = edges[j     + half];
        const int2 eB = edges[j + 2 + half];
        const int2 eC = edges[j + 4 + half];
        const int2 eD = edges[j + 6 + half];
        const ushort4 vA = *(const ushort4*)(hb + (size_t)eA.x * DD + c4);
        const ushort4 vB = *(const ushort4*)(hb + (size_t)eB.x * DD + c4);
        const ushort4 vC = *(const ushort4*)(hb + (size_t)eC.x * DD + c4);
        const ushort4 vD = *(const ushort4*)(hb + (size_t)eD.x * DD + c4);
        const float wA = __int_as_float(eA.y), wB = __int_as_float(eB.y);
        const float wC = __int_as_float(eC.y), wD = __int_as_float(eD.y);
        a0.x = fmaf(b2f(vA.x), wA, a0.x); a0.y = fmaf(b2f(vA.y), wA, a0.y);
        a0.z = fmaf(b2f(vA.z), wA, a0.z); a0.w = fmaf(b2f(vA.w), wA, a0.w);
        a1.x = fmaf(b2f(vB.x), wB, a1.x); a1.y = fmaf(b2f(vB.y), wB, a1.y);
        a1.z = fmaf(b2f(vB.z), wB, a1.z); a1.w = fmaf(b2f(vB.w), wB, a1.w);
        a0.x = fmaf(b2f(vC.x), wC, a0.x); a0.y = fmaf(b2f(vC.y), wC, a0.y);
        a0.z = fmaf(b2f(vC.z), wC, a0.z); a0.w = fmaf(b2f(vC.w), wC, a0.w);
        a1.x = fmaf(b2f(vD.x), wD, a1.x); a1.y = fmaf(b2f(vD.y), wD, a1.y);
        a1.z = fmaf(b2f(vD.z), wD, a1.z); a1.w = fmaf(b2f(vD.w), wD, a1.w);
    }
    for (; j < s1; j += 2) {
        const int idx = j + half;
        const bool ok = idx < s1;
        const int2 e = edges[ok ? idx : s1 - 1];
        const float wt = ok ? __int_as_float(e.y) : 0.f;
        const ushort4 v = *(const ushort4*)(hb + (size_t)e.x * DD + c4);
        a0.x = fmaf(b2f(v.x), wt, a0.x); a0.y = fmaf(b2f(v.y), wt, a0.y);
        a0.z = fmaf(b2f(v.z), wt, a0.z); a0.w = fmaf(b2f(v.w), wt, a0.w);
    }
    float4 tot = make_float4(a0.x + a1.x, a0.y + a1.y, a0.z + a1.z, a0.w + a1.w);
    float4 oth;
    oth.x = __shfl_xor(tot.x, 32);
    oth.y = __shfl_xor(tot.y, 32);
    oth.z = __shfl_xor(tot.z, 32);
    oth.w = __shfl_xor(tot.w, 32);
    if (half == 0) {
        tot.x += oth.x; tot.y += oth.y; tot.z += oth.z; tot.w += oth.w;
        ushort4 o;
        o.x = bf16rne(tot.x); o.y = bf16rne(tot.y);
        o.z = bf16rne(tot.z); o.w = bf16rne(tot.w);
        *(ushort4*)(aggb + (size_t)w * DD + c4) = o;
    }
}

// ===========================================================================
// FUSED dual-source MFMA GEMM, BF16-A variant:
//   X = aggb @ Wrel + hb @ Wroot + bias      (X fp32)
// A operands are raw bf16 rows: the 16 B load IS the MFMA fragment (no split,
// no conversion). B uses 2 split components (error 2^-17, << A's 2^-9).
// 4 stages as R8-proven; R4-proven trivial epilogue (NO fused LN -- banned).
// No aliasing: aggb/hb inputs, X output are disjoint buffers.
// ===========================================================================
__global__ __launch_bounds__(256, 3) void k_gemm2(
    const unsigned short* __restrict__ aggb,
    const unsigned short* __restrict__ hb,
    const short* __restrict__ packRel, const short* __restrict__ packRoot,
    const float* __restrict__ bias, float* __restrict__ X, int N)
{
    __shared__ short sB[16384];   // one 64-K chunk, 2 components, 32 KB

    const int t256 = threadIdx.x;
    const int lane = t256 & 63;
    const int w    = t256 >> 6;
    const int q    = lane >> 4;
    const int r16  = lane & 15;
    const int rowbase = blockIdx.x * CBM + w * 32;

    f32x4 acc[2][8];
    #pragma unroll
    for (int mt = 0; mt < 2; ++mt)
        #pragma unroll
        for (int t = 0; t < 8; ++t) acc[mt][t] = (f32x4)(0.f);

    for (int stage = 0; stage < 4; ++stage) {
        const unsigned short* A = (stage < 2) ? aggb : hb;
        const short* pk = ((stage < 2) ? packRel : packRoot)
                          + (size_t)(stage & 1) * 24576;
        const int kb = (stage & 1) * 64;
        if (stage) __syncthreads();
        {   // copy comps 1+2 of the chunk: 16384 shorts = 2048 uint4
            const uint4* srcp = (const uint4*)pk;
            uint4* dstp = (uint4*)sB;
            #pragma unroll
            for (int i = 0; i < 8; ++i)
                dstp[i * 256 + t256] = srcp[i * 256 + t256];
        }
        __syncthreads();

        #pragma unroll
        for (int s = 0; s < 2; ++s) {
            const int kq = kb + s * 32 + q * 8;
            fragT a[2];
            #pragma unroll
            for (int mt = 0; mt < 2; ++mt) {
                const int row = rowbase + mt * 16 + r16;
                if (row < N)
                    a[mt] = *(const fragT*)(A + (size_t)row * DD + kq);
                else
                    a[mt] = (fragT)(short)0;
            }
            const short* sbase = sB + s * 4096 + lane * 8;
            #pragma unroll
            for (int t = 0; t < 8; ++t) {
                const fragT b1c = *(const fragT*)(sbase + t * 512);
                const fragT b2c = *(const fragT*)(sbase + 8192 + t * 512);
                #pragma unroll
                for (int mt = 0; mt < 2; ++mt) {
                    acc[mt][t] = __builtin_amdgcn_mfma_f32_16x16x32_bf16(a[mt], b1c, acc[mt][t], 0, 0, 0);
                    acc[mt][t] = __builtin_amdgcn_mfma_f32_16x16x32_bf16(a[mt], b2c, acc[mt][t], 0, 0, 0);
                }
            }
        }
    }

    // epilogue (proven trivial form): X[row][col] = acc + bias[col]
    #pragma unroll
    for (int mt = 0; mt < 2; ++mt) {
        #pragma unroll
        for (int r = 0; r < 4; ++r) {
            const int row = rowbase + mt * 16 + q * 4 + r;
            if (row < N) {
                #pragma unroll
                for (int t = 0; t < 8; ++t) {
                    const int col = t * 16 + r16;
                    X[(size_t)row * DD + col] = acc[mt][t][r] + bias[col];
                }
            }
        }
    }
}

// ===========================================================================
// In-place row LayerNorm + PReLU on X [N x 128], fp32 exact; additionally
// emits a bf16(RNE) copy into hb when hb != 0. (R7-proven, byte-identical.)
// ===========================================================================
__global__ __launch_bounds__(256) void k_ln(
    float* X, unsigned short* hb,
    const float* __restrict__ lng, const float* __restrict__ lnb,
    const float* __restrict__ alpha_p, int N)
{
    const int row = blockIdx.x * 4 + (threadIdx.x >> 6);
    if (row >= N) return;
    const int lane = threadIdx.x & 63;
    float2 v = *(float2*)(X + (size_t)row * DD + lane * 2);
    float s  = v.x + v.y;
    float s2 = fmaf(v.x, v.x, v.y * v.y);
    #pragma unroll
    for (int off = 32; off > 0; off >>= 1) {
        s  += __shfl_xor(s,  off, 64);
        s2 += __shfl_xor(s2, off, 64);
    }
    const float mean = s * (1.f / 128.f);
    float var = s2 * (1.f / 128.f) - mean * mean;
    var = var < 0.f ? 0.f : var;
    const float rstd = rsqrtf(var + 1e-5f);
    const float2 g = *(const float2*)(lng + lane * 2);
    const float2 b = *(const float2*)(lnb + lane * 2);
    const float alpha = alpha_p[0];
    float y0 = (v.x - mean) * rstd * g.x + b.x;
    float y1 = (v.y - mean) * rstd * g.y + b.y;
    y0 = (y0 >= 0.f) ? y0 : alpha * y0;
    y1 = (y1 >= 0.f) ? y1 : alpha * y1;
    *(float2*)(X + (size_t)row * DD + lane * 2) = make_float2(y0, y1);
    if (hb) {
        ushort2 hv;
        hv.x = bf16rne(y0);
        hv.y = bf16rne(y1);
        *(ushort2*)(hb + (size_t)row * DD + lane * 2) = hv;
    }
}

// ===========================================================================
// Classifier (MFMA): logits = LN(relu(h @ W1 + b1)) @ W2 + b2
// (proven, byte-identical; consumes fp32 h = X after last in-place LN.)
// ===========================================================================
__global__ __launch_bounds__(256, 3) void k_cls(
    const float* __restrict__ hin, const short* __restrict__ packC,
    const float* __restrict__ b1, const float* __restrict__ lng,
    const float* __restrict__ lnb, const float* __restrict__ W2,
    const float* __restrict__ b2, float* __restrict__ out, int N)
{
    __shared__ short sB[24576];   // one 64-K chunk, 3 components, 48 KB

    const int t256 = threadIdx.x;
    const int lane = t256 & 63;
    const int w    = t256 >> 6;
    const int q    = lane >> 4;
    const int r16  = lane & 15;
    const int rowbase = blockIdx.x * CBM + w * 32;

    f32x4 acc[2][8];
    #pragma unroll
    for (int mt = 0; mt < 2; ++mt)
        #pragma unroll
        for (int t = 0; t < 8; ++t) acc[mt][t] = (f32x4)(0.f);

    for (int c = 0; c < 2; ++c) {
        if (c) __syncthreads();
        {   // copy 48 KB pre-packed chunk (3072 uint4)
            const uint4* srcp = (const uint4*)(packC + (size_t)c * 24576);
            uint4* dstp = (uint4*)sB;
            #pragma unroll
            for (int i = 0; i < 12; ++i)
                dstp[i * 256 + t256] = srcp[i * 256 + t256];
        }
        __syncthreads();

        const int kb = c * 64;
        #pragma unroll
        for (int s = 0; s < 2; ++s) {
            const int kq = kb + s * 32 + q * 8;
            fragT a1[2], a2[2], a3[2];
            #pragma unroll
            for (int mt = 0; mt < 2; ++mt) {
                const int row = rowbase + mt * 16 + r16;
                float4 v0 = make_float4(0.f, 0.f, 0.f, 0.f);
                float4 v1 = make_float4(0.f, 0.f, 0.f, 0.f);
                if (row < N) {
                    v0 = *(const float4*)(hin + (size_t)row * DD + kq);
                    v1 = *(const float4*)(hin + (size_t)row * DD + kq + 4);
                }
                split8_3(v0, v1, a1[mt], a2[mt], a3[mt]);
            }
            const short* sbase = sB + s * 4096 + lane * 8;
            #pragma unroll
            for (int t = 0; t < 8; ++t) {
                const fragT b1c = *(const fragT*)(sbase + t * 512);
                const fragT b2c = *(const fragT*)(sbase + 8192 + t * 512);
                const fragT b3c = *(const fragT*)(sbase + 16384 + t * 512);
                #pragma unroll
                for (int mt = 0; mt < 2; ++mt) {
                    acc[mt][t] = __builtin_amdgcn_mfma_f32_16x16x32_bf16(a1[mt], b1c, acc[mt][t], 0, 0, 0);
                    acc[mt][t] = __builtin_amdgcn_mfma_f32_16x16x32_bf16(a2[mt], b1c, acc[mt][t], 0, 0, 0);
                    acc[mt][t] = __builtin_amdgcn_mfma_f32_16x16x32_bf16(a1[mt], b2c, acc[mt][t], 0, 0, 0);
                    acc[mt][t] = __builtin_amdgcn_mfma_f32_16x16x32_bf16(a3[mt], b1c, acc[mt][t], 0, 0, 0);
                    acc[mt][t] = __builtin_amdgcn_mfma_f32_16x16x32_bf16(a2[mt], b2c, acc[mt][t], 0, 0, 0);
                    acc[mt][t] = __builtin_amdgcn_mfma_f32_16x16x32_bf16(a1[mt], b3c, acc[mt][t], 0, 0, 0);
                }
            }
        }
    }

    float b1v[8], gvv[8], bvv[8], w2c0[8], w2c1[8];
    #pragma unroll
    for (int t = 0; t < 8; ++t) {
        const int col = t * 16 + r16;
        b1v[t] = b1[col]; gvv[t] = lng[col]; bvv[t] = lnb[col];
        const float2 w2 = *(const float2*)(W2 + col * 2);
        w2c0[t] = w2.x; w2c1[t] = w2.y;
    }
    const float b2v0 = b2[0], b2v1 = b2[1];

    #pragma unroll
    for (int mt = 0; mt < 2; ++mt) {
        #pragma unroll
        for (int r = 0; r < 4; ++r) {
            const int row = rowbase + mt * 16 + q * 4 + r;
            float xv[8];
            float s = 0.f, s2 = 0.f;
            #pragma unroll
            for (int t = 0; t < 8; ++t) {
                float x = acc[mt][t][r] + b1v[t];
                x = x > 0.f ? x : 0.f;      // relu
                xv[t] = x; s += x; s2 = fmaf(x, x, s2);
            }
            #pragma unroll
            for (int off = 8; off > 0; off >>= 1) {
                s  += __shfl_xor(s,  off, 16);
                s2 += __shfl_xor(s2, off, 16);
            }
            const float mean = s * (1.f / 128.f);
            float var = s2 * (1.f / 128.f) - mean * mean;
            var = var < 0.f ? 0.f : var;
            const float rstd = rsqrtf(var + 1e-5f);
            float p0 = 0.f, p1 = 0.f;
            #pragma unroll
            for (int t = 0; t < 8; ++t) {
                const float z = (xv[t] - mean) * rstd * gvv[t] + bvv[t];
                p0 = fmaf(z, w2c0[t], p0);
                p1 = fmaf(z, w2c1[t], p1);
            }
            #pragma unroll
            for (int off = 8; off > 0; off >>= 1) {
                p0 += __shfl_xor(p0, off, 16);
                p1 += __shfl_xor(p1, off, 16);
            }
            if (r16 == 0 && row < N) {
                out[row * 2 + 0] = p0 + b2v0;
                out[row * 2 + 1] = p1 + b2v1;
            }
        }
    }
}

// ===========================================================================
extern "C" void kernel_launch(void* const* d_in, const int* in_sizes, int n_in,
                              void* d_out, int out_size, void* d_ws, size_t ws_size,
                              hipStream_t stream) {
    const float* features = (const float*)d_in[0];
    const int*   eidx     = (const int*)  d_in[1];
    const float* ew       = (const float*)d_in[2];
    const float* Wrel     = (const float*)d_in[3];
    const float* Wroot    = (const float*)d_in[4];
    const float* bias     = (const float*)d_in[5];
    const float* lng      = (const float*)d_in[6];
    const float* lnb      = (const float*)d_in[7];
    const float* alpha    = (const float*)d_in[8];
    const float* W1       = (const float*)d_in[9];
    const float* b1       = (const float*)d_in[10];
    const float* clng     = (const float*)d_in[11];
    const float* clnb     = (const float*)d_in[12];
    const float* W2       = (const float*)d_in[13];
    const float* b2       = (const float*)d_in[14];

    const int N = in_sizes[0] / DD;
    const int E = in_sizes[2];
    const int L = in_sizes[8];

    // workspace (~143 MB of >=155 MB)
    float* X       = (float*)d_ws;                       // N*128 f (51.2 MB)
    unsigned short* hbA  = (unsigned short*)(X + (size_t)N * DD);   // 25.6 MB
    unsigned short* hbB  = hbA + (size_t)N * DD;                    // 25.6 MB
    unsigned short* aggb = hbB + (size_t)N * DD;                    // 25.6 MB
    int2*  edges_s = (int2*)(aggb + (size_t)N * DD);     // E (12.8 MB)
    int*   counts  = (int*)(edges_s + E);                // N
    int*   starts  = counts + N;                         // N+1
    int*   bsum    = starts + N + 1;                     // 258
    int*   cursor1 = bsum + 258;                         // 256 (+5 pad)
    short* packAll = (short*)(cursor1 + 261);            // (2L+1)*49152 shorts
    int4*  tmp     = (int4*)X;                           // E recs, dead before layers

    const int* src = eidx;
    const int* dst = eidx + E;

    const int eb      = (E + 255) / 256;
    const int eb2k    = (E + 2047) / 2048;
    const int nb      = (N + 1023) / 1024;
    const int NBk     = (N + SPB - 1) / SPB;
    const int mm_blocks  = (N + CBM - 1) / CBM;
    const int ln_blocks  = (N + 3) / 4;
    const int ga_blocks  = (N * 64 + 255) / 256;
    const int cv_blocks  = (N * DD / 4 + 255) / 256;

    // ---- pack all weight matrices (W_rel[l], W_root[l], cls W1) ----
    for (int l = 0; l < L; ++l) {
        k_pack_cls<<<32, 64, 0, stream>>>(Wrel  + (size_t)l * DD * DD,
                                          packAll + (size_t)(2 * l)     * 49152);
        k_pack_cls<<<32, 64, 0, stream>>>(Wroot + (size_t)l * DD * DD,
                                          packAll + (size_t)(2 * l + 1) * 49152);
    }
    k_pack_cls<<<32, 64, 0, stream>>>(W1, packAll + (size_t)(2 * L) * 49152);

    // ---- features -> bf16 (layer-0 h) ----
    k_tobf16<<<cv_blocks, 256, 0, stream>>>(features, hbA, N * DD / 4);

    // ---- build CSR by dst (once per call) ----
    hipMemsetAsync(counts, 0, (size_t)N * sizeof(int), stream);
    k_hist  <<<eb, 256, 0, stream>>>(dst, counts, E);
    k_scan1 <<<nb, 256, 0, stream>>>(counts, counts, bsum, N);   // in-place
    k_scan2 <<<1,  256, 0, stream>>>(bsum, nb);
    k_scan3 <<<(N + 255) / 256, 256, 0, stream>>>(counts, bsum, starts, cursor1, N, E);
    k_bucket<<<eb2k, 256, 0, stream>>>(src, dst, ew, cursor1, tmp, E);
    k_place <<<NBk, 256, 0, stream>>>(tmp, starts, edges_s, N, E);

    // ---- layers: gather(bf16->bf16) -> GEMM2(bf16 A) -> LN(fp32, +bf16) ----
    unsigned short* hbIn  = hbA;
    unsigned short* hbOut = hbB;
    for (int l = 0; l < L; ++l) {
        k_gather_bf16<<<ga_blocks, 256, 0, stream>>>(hbIn, starts, edges_s, aggb, N);
        k_gemm2<<<mm_blocks, 256, 0, stream>>>(
            aggb, hbIn,
            packAll + (size_t)(2 * l)     * 49152,
            packAll + (size_t)(2 * l + 1) * 49152,
            bias + l * DD, X, N);
        k_ln<<<ln_blocks, 256, 0, stream>>>(
            X, (l < L - 1) ? hbOut : (unsigned short*)nullptr,
            lng + l * DD, lnb + l * DD, alpha + l, N);
        unsigned short* t = hbIn; hbIn = hbOut; hbOut = t;
    }
    k_cls<<<mm_blocks, 256, 0, stream>>>(X, packAll + (size_t)(2 * L) * 49152,
                                         b1, clng, clnb, W2, b2,
                                         (float*)d_out, N);
}